// Round 21
// baseline (240.578 us; speedup 1.0000x reference)
//
#include <hip/hip_runtime.h>
#include <hip/hip_bf16.h>

#define TQ_D   1024
#define TQ_KC  16
#define MERGE_K 512          // OpenBLAS KC-panel boundary (proven R9)
#define TQ_TOL  1.0e-3f      // >= 2x worst-case |y_mfma - y_ref| bound
#define LCAP    1024         // per-block LDS suspect-list capacity

typedef __attribute__((ext_vector_type(8))) short bf16x8;
typedef __attribute__((ext_vector_type(8))) unsigned short ushort8;
typedef __attribute__((ext_vector_type(4))) float f32x4;

__device__ __forceinline__ unsigned short f2bf(float f) {
    union { __hip_bfloat16 h; unsigned short s; } u;
    u.h = __float2bfloat16(f);
    return u.s;
}
__device__ __forceinline__ float bf2f(unsigned short s) {
    union { unsigned int u; float f; } v;
    v.u = (unsigned int)s << 16;
    return v.f;
}

// ---------------------------------------------------------------------------
// Pre-pass: planar hi/lo bf16 split. h = bf16(x); l = bf16(x - f32(h)).
// Each element converted exactly ONCE (K1 previously re-converted X 8x, Pi 32x).
// ---------------------------------------------------------------------------
__global__ __launch_bounds__(256)
void tq_split(const float* __restrict__ In,
              unsigned short* __restrict__ Hi,
              unsigned short* __restrict__ Lo,
              int total4)
{
    for (int i = blockIdx.x * 256 + threadIdx.x; i < total4;
         i += gridDim.x * 256) {
        const float4 v = *((const float4*)In + i);
        ushort4 h, l;
        h.x = f2bf(v.x); l.x = f2bf(v.x - bf2f(h.x));
        h.y = f2bf(v.y); l.y = f2bf(v.y - bf2f(h.y));
        h.z = f2bf(v.z); l.z = f2bf(v.z - bf2f(h.z));
        h.w = f2bf(v.w); l.w = f2bf(v.w - bf2f(h.w));
        *((ushort4*)Hi + i) = h;
        *((ushort4*)Lo + i) = l;
    }
}

// ---------------------------------------------------------------------------
// K1-MFMA (pre-split inputs): y = x @ Pi^T, 3-term bf16 hi/lo MFMA, f32 acc,
// literal f32 argmin. Staging = pure ushort8 copies (no conversion VALU).
// Suspects aggregated per-block in LDS, ONE global atomicAdd per block.
// ---------------------------------------------------------------------------
__global__ __launch_bounds__(256)
void tq_rq_mfma_pre(const unsigned short* __restrict__ Xh,
                    const unsigned short* __restrict__ Xl,
                    const unsigned short* __restrict__ Ph,
                    const unsigned short* __restrict__ Pl,
                    const float* __restrict__ Cent,
                    float* __restrict__ OutIdx,
                    unsigned* __restrict__ Counter,
                    unsigned* __restrict__ List,
                    unsigned cap)
{
    __shared__ unsigned short XhS[128][40];
    __shared__ unsigned short XlS[128][40];
    __shared__ unsigned short PhS[128][40];
    __shared__ unsigned short PlS[128][40];
    __shared__ unsigned lcount;
    __shared__ unsigned gbase;
    __shared__ unsigned llist[LCAP];

    const int tid  = threadIdx.x;
    const int lane = tid & 63;
    const int wv   = tid >> 6;
    const int m0 = blockIdx.y * 128;
    const int n0 = blockIdx.x * 128;
    const int wr = (wv >> 1) * 64;
    const int wc = (wv & 1) * 64;
    const int l15 = lane & 15;
    const int k8  = (lane >> 4) * 8;

    const int srow = tid >> 1;
    const int scol = (tid & 1) * 16;

    const unsigned short* aPh = Xh + (size_t)(m0 + srow) * TQ_D + scol;
    const unsigned short* aPl = Xl + (size_t)(m0 + srow) * TQ_D + scol;
    const unsigned short* bPh = Ph + (size_t)(n0 + srow) * TQ_D + scol;
    const unsigned short* bPl = Pl + (size_t)(n0 + srow) * TQ_D + scol;

    if (tid == 0) lcount = 0;

    f32x4 acc[4][4];
#pragma unroll
    for (int i = 0; i < 4; ++i)
#pragma unroll
        for (int j = 0; j < 4; ++j)
#pragma unroll
            for (int r = 0; r < 4; ++r) acc[i][j][r] = 0.0f;

    ushort8 vah[2], val[2], vbh[2], vbl[2];
#pragma unroll
    for (int q = 0; q < 2; ++q) {
        vah[q] = *(const ushort8*)(aPh + 8 * q);
        val[q] = *(const ushort8*)(aPl + 8 * q);
        vbh[q] = *(const ushort8*)(bPh + 8 * q);
        vbl[q] = *(const ushort8*)(bPl + 8 * q);
    }
#pragma unroll
    for (int q = 0; q < 2; ++q) {
        *(ushort8*)&XhS[srow][scol + 8 * q] = vah[q];
        *(ushort8*)&XlS[srow][scol + 8 * q] = val[q];
        *(ushort8*)&PhS[srow][scol + 8 * q] = vbh[q];
        *(ushort8*)&PlS[srow][scol + 8 * q] = vbl[q];
    }
    __syncthreads();   // also covers lcount init

    for (int kt = 0; kt < 32; ++kt) {
        const bool more = (kt + 1) < 32;
        if (more) {
            const int off = (kt + 1) * 32;
#pragma unroll
            for (int q = 0; q < 2; ++q) {
                vah[q] = *(const ushort8*)(aPh + off + 8 * q);
                val[q] = *(const ushort8*)(aPl + off + 8 * q);
                vbh[q] = *(const ushort8*)(bPh + off + 8 * q);
                vbl[q] = *(const ushort8*)(bPl + off + 8 * q);
            }
        }

        bf16x8 afh[4], afl[4], bfh[4], bfl[4];
#pragma unroll
        for (int i = 0; i < 4; ++i) {
            afh[i] = *(const bf16x8*)&XhS[wr + i * 16 + l15][k8];
            afl[i] = *(const bf16x8*)&XlS[wr + i * 16 + l15][k8];
        }
#pragma unroll
        for (int j = 0; j < 4; ++j) {
            bfh[j] = *(const bf16x8*)&PhS[wc + j * 16 + l15][k8];
            bfl[j] = *(const bf16x8*)&PlS[wc + j * 16 + l15][k8];
        }

#pragma unroll
        for (int i = 0; i < 4; ++i)
#pragma unroll
            for (int j = 0; j < 4; ++j) {
                acc[i][j] = __builtin_amdgcn_mfma_f32_16x16x32_bf16(
                    afh[i], bfh[j], acc[i][j], 0, 0, 0);
                acc[i][j] = __builtin_amdgcn_mfma_f32_16x16x32_bf16(
                    afl[i], bfh[j], acc[i][j], 0, 0, 0);
                acc[i][j] = __builtin_amdgcn_mfma_f32_16x16x32_bf16(
                    afh[i], bfl[j], acc[i][j], 0, 0, 0);
            }

        if (more) {
            __syncthreads();
#pragma unroll
            for (int q = 0; q < 2; ++q) {
                *(ushort8*)&XhS[srow][scol + 8 * q] = vah[q];
                *(ushort8*)&XlS[srow][scol + 8 * q] = val[q];
                *(ushort8*)&PhS[srow][scol + 8 * q] = vbh[q];
                *(ushort8*)&PlS[srow][scol + 8 * q] = vbl[q];
            }
            __syncthreads();
        }
    }

    float c[TQ_KC];
#pragma unroll
    for (int q = 0; q < TQ_KC; ++q) c[q] = Cent[q];

#pragma unroll
    for (int i = 0; i < 4; ++i)
#pragma unroll
        for (int j = 0; j < 4; ++j)
#pragma unroll
            for (int r = 0; r < 4; ++r) {
                const int row = m0 + wr + i * 16 + (lane >> 4) * 4 + r;
                const int col = n0 + wc + j * 16 + l15;
                const float y = acc[i][j][r];
                int best = 0;
                float bd = fabsf(y - c[0]);
#pragma unroll
                for (int q = 1; q < TQ_KC; ++q) {
                    const float d = fabsf(y - c[q]);
                    if (d < bd) { bd = d; best = q; }
                }
                float dist = 1e30f;
#pragma unroll
                for (int q = 0; q < TQ_KC - 1; ++q) {
                    const float mid = 0.5f * (c[q] + c[q + 1]);
                    dist = fminf(dist, fabsf(y - mid));
                }
                if (dist < TQ_TOL) {
                    const unsigned id = ((unsigned)row << 10) | (unsigned)col;
                    const unsigned ls = atomicAdd(&lcount, 1u);
                    if (ls < LCAP) {
                        llist[ls] = id;
                    } else {
                        const unsigned gs = atomicAdd(Counter, 1u);
                        if (gs < cap) List[gs] = id;
                    }
                }
                OutIdx[(size_t)row * TQ_D + col] = (float)best;
            }

    __syncthreads();
    if (tid == 0) {
        const unsigned cnt = min(lcount, (unsigned)LCAP);
        gbase = (cnt > 0) ? atomicAdd(Counter, cnt) : 0u;
    }
    __syncthreads();
    const unsigned cnt = min(lcount, (unsigned)LCAP);
    for (unsigned s = tid; s < cnt; s += 256) {
        const unsigned g = gbase + s;
        if (g < cap) List[g] = llist[s];
    }
}

// ---------------------------------------------------------------------------
// Fallback K1 (proven R20): in-kernel hi/lo split (used when ws_size too small).
// ---------------------------------------------------------------------------
__global__ __launch_bounds__(256)
void tq_rq_mfma_fused(const float* __restrict__ X,
                      const float* __restrict__ Pi,
                      const float* __restrict__ Cent,
                      float* __restrict__ OutIdx,
                      unsigned* __restrict__ Counter,
                      unsigned* __restrict__ List,
                      unsigned cap)
{
    __shared__ unsigned short XhS[128][40];
    __shared__ unsigned short XlS[128][40];
    __shared__ unsigned short PhS[128][40];
    __shared__ unsigned short PlS[128][40];
    __shared__ unsigned lcount;
    __shared__ unsigned gbase;
    __shared__ unsigned llist[LCAP];

    const int tid  = threadIdx.x;
    const int lane = tid & 63;
    const int wv   = tid >> 6;
    const int m0 = blockIdx.y * 128;
    const int n0 = blockIdx.x * 128;
    const int wr = (wv >> 1) * 64;
    const int wc = (wv & 1) * 64;
    const int l15 = lane & 15;
    const int k8  = (lane >> 4) * 8;

    const int srow = tid >> 1;
    const int scol = (tid & 1) * 16;

    const float* aP = X  + (size_t)(m0 + srow) * TQ_D + scol;
    const float* bP = Pi + (size_t)(n0 + srow) * TQ_D + scol;

    if (tid == 0) lcount = 0;

    f32x4 acc[4][4];
#pragma unroll
    for (int i = 0; i < 4; ++i)
#pragma unroll
        for (int j = 0; j < 4; ++j)
#pragma unroll
            for (int r = 0; r < 4; ++r) acc[i][j][r] = 0.0f;

    float4 va[4], vb[4];
#pragma unroll
    for (int q = 0; q < 4; ++q) {
        va[q] = *(const float4*)(aP + 4 * q);
        vb[q] = *(const float4*)(bP + 4 * q);
    }

#pragma unroll
    for (int q = 0; q < 4; ++q) {
        ushort4 ah, al, bh, bl;
        const float* fa = (const float*)&va[q];
        const float* fb = (const float*)&vb[q];
        ah.x = f2bf(fa[0]); al.x = f2bf(fa[0] - bf2f(ah.x));
        ah.y = f2bf(fa[1]); al.y = f2bf(fa[1] - bf2f(ah.y));
        ah.z = f2bf(fa[2]); al.z = f2bf(fa[2] - bf2f(ah.z));
        ah.w = f2bf(fa[3]); al.w = f2bf(fa[3] - bf2f(ah.w));
        bh.x = f2bf(fb[0]); bl.x = f2bf(fb[0] - bf2f(bh.x));
        bh.y = f2bf(fb[1]); bl.y = f2bf(fb[1] - bf2f(bh.y));
        bh.z = f2bf(fb[2]); bl.z = f2bf(fb[2] - bf2f(bh.z));
        bh.w = f2bf(fb[3]); bl.w = f2bf(fb[3] - bf2f(bh.w));
        *(ushort4*)&XhS[srow][scol + 4 * q] = ah;
        *(ushort4*)&XlS[srow][scol + 4 * q] = al;
        *(ushort4*)&PhS[srow][scol + 4 * q] = bh;
        *(ushort4*)&PlS[srow][scol + 4 * q] = bl;
    }
    __syncthreads();

    for (int kt = 0; kt < 32; ++kt) {
        const bool more = (kt + 1) < 32;
        if (more) {
            const float* ap = aP + (kt + 1) * 32;
            const float* bp = bP + (kt + 1) * 32;
#pragma unroll
            for (int q = 0; q < 4; ++q) {
                va[q] = *(const float4*)(ap + 4 * q);
                vb[q] = *(const float4*)(bp + 4 * q);
            }
        }

        bf16x8 afh[4], afl[4], bfh[4], bfl[4];
#pragma unroll
        for (int i = 0; i < 4; ++i) {
            afh[i] = *(const bf16x8*)&XhS[wr + i * 16 + l15][k8];
            afl[i] = *(const bf16x8*)&XlS[wr + i * 16 + l15][k8];
        }
#pragma unroll
        for (int j = 0; j < 4; ++j) {
            bfh[j] = *(const bf16x8*)&PhS[wc + j * 16 + l15][k8];
            bfl[j] = *(const bf16x8*)&PlS[wc + j * 16 + l15][k8];
        }

#pragma unroll
        for (int i = 0; i < 4; ++i)
#pragma unroll
            for (int j = 0; j < 4; ++j) {
                acc[i][j] = __builtin_amdgcn_mfma_f32_16x16x32_bf16(
                    afh[i], bfh[j], acc[i][j], 0, 0, 0);
                acc[i][j] = __builtin_amdgcn_mfma_f32_16x16x32_bf16(
                    afl[i], bfh[j], acc[i][j], 0, 0, 0);
                acc[i][j] = __builtin_amdgcn_mfma_f32_16x16x32_bf16(
                    afh[i], bfl[j], acc[i][j], 0, 0, 0);
            }

        if (more) {
            __syncthreads();
#pragma unroll
            for (int q = 0; q < 4; ++q) {
                ushort4 ah, al, bh, bl;
                const float* fa = (const float*)&va[q];
                const float* fb = (const float*)&vb[q];
                ah.x = f2bf(fa[0]); al.x = f2bf(fa[0] - bf2f(ah.x));
                ah.y = f2bf(fa[1]); al.y = f2bf(fa[1] - bf2f(ah.y));
                ah.z = f2bf(fa[2]); al.z = f2bf(fa[2] - bf2f(ah.z));
                ah.w = f2bf(fa[3]); al.w = f2bf(fa[3] - bf2f(ah.w));
                bh.x = f2bf(fb[0]); bl.x = f2bf(fb[0] - bf2f(bh.x));
                bh.y = f2bf(fb[1]); bl.y = f2bf(fb[1] - bf2f(bh.y));
                bh.z = f2bf(fb[2]); bl.z = f2bf(fb[2] - bf2f(bh.z));
                bh.w = f2bf(fb[3]); bl.w = f2bf(fb[3] - bf2f(bh.w));
                *(ushort4*)&XhS[srow][scol + 4 * q] = ah;
                *(ushort4*)&XlS[srow][scol + 4 * q] = al;
                *(ushort4*)&PhS[srow][scol + 4 * q] = bh;
                *(ushort4*)&PlS[srow][scol + 4 * q] = bl;
            }
            __syncthreads();
        }
    }

    float c[TQ_KC];
#pragma unroll
    for (int q = 0; q < TQ_KC; ++q) c[q] = Cent[q];

#pragma unroll
    for (int i = 0; i < 4; ++i)
#pragma unroll
        for (int j = 0; j < 4; ++j)
#pragma unroll
            for (int r = 0; r < 4; ++r) {
                const int row = m0 + wr + i * 16 + (lane >> 4) * 4 + r;
                const int col = n0 + wc + j * 16 + l15;
                const float y = acc[i][j][r];
                int best = 0;
                float bd = fabsf(y - c[0]);
#pragma unroll
                for (int q = 1; q < TQ_KC; ++q) {
                    const float d = fabsf(y - c[q]);
                    if (d < bd) { bd = d; best = q; }
                }
                float dist = 1e30f;
#pragma unroll
                for (int q = 0; q < TQ_KC - 1; ++q) {
                    const float mid = 0.5f * (c[q] + c[q + 1]);
                    dist = fminf(dist, fabsf(y - mid));
                }
                if (dist < TQ_TOL) {
                    const unsigned id = ((unsigned)row << 10) | (unsigned)col;
                    const unsigned ls = atomicAdd(&lcount, 1u);
                    if (ls < LCAP) {
                        llist[ls] = id;
                    } else {
                        const unsigned gs = atomicAdd(Counter, 1u);
                        if (gs < cap) List[gs] = id;
                    }
                }
                OutIdx[(size_t)row * TQ_D + col] = (float)best;
            }

    __syncthreads();
    if (tid == 0) {
        const unsigned cnt = min(lcount, (unsigned)LCAP);
        gbase = (cnt > 0) ? atomicAdd(Counter, cnt) : 0u;
    }
    __syncthreads();
    const unsigned cnt = min(lcount, (unsigned)LCAP);
    for (unsigned s = tid; s < cnt; s += 256) {
        const unsigned g = gbase + s;
        if (g < cap) List[g] = llist[s];
    }
}

// ---------------------------------------------------------------------------
// Fixup (LDS-staged): 8 suspects/block. 256 threads stage 8x(X row + Pi row)
// = 64KB into LDS (all loads in flight at once), then 16 threads run the two
// independent 512-wide serial panel chains (exact R9 realization: in-order
// fmaf, single accumulator per panel), merge a1+a2, literal argmin.
// ---------------------------------------------------------------------------
__global__ __launch_bounds__(256)
void tq_fixup_lds(const float* __restrict__ X,
                  const float* __restrict__ Pi,
                  const float* __restrict__ Cent,
                  float* __restrict__ OutIdx,
                  const unsigned* __restrict__ Counter,
                  const unsigned* __restrict__ List,
                  unsigned cap)
{
    __shared__ float Rows[8][2][1024];   // [suspect][0=X,1=Pi][k]
    __shared__ float part[8][2];
    __shared__ unsigned ids[8];

    const int tid = threadIdx.x;
    const unsigned count = min(*Counter, cap);

    for (unsigned base = blockIdx.x * 8; base < count; base += gridDim.x * 8) {
        const unsigned nsus = min(8u, count - base);

        if (tid < 8) ids[tid] = (tid < nsus) ? List[base + tid] : 0u;
        __syncthreads();

        // stage: 4096 float4 slots; lin = q*256 + tid
#pragma unroll
        for (int q = 0; q < 16; ++q) {
            const int lin = q * 256 + tid;
            const int sus = lin >> 9;            // 512 float4 per suspect
            const int rowsel = (lin >> 8) & 1;   // 0 = X row, 1 = Pi row
            const int f4 = lin & 255;
            if ((unsigned)sus < nsus) {
                const unsigned id = ids[sus];
                const int m = id >> 10;
                const int n = id & (TQ_D - 1);
                const float* src = rowsel ? (Pi + (size_t)n * TQ_D)
                                          : (X + (size_t)m * TQ_D);
                *(float4*)&Rows[sus][rowsel][f4 * 4] =
                    *(const float4*)(src + f4 * 4);
            }
        }
        __syncthreads();

        // chains: tid<16 -> suspect tid>>1, panel tid&1
        if (tid < 16 && (unsigned)(tid >> 1) < nsus) {
            const int sus = tid >> 1;
            const int p = tid & 1;
            const int kb = p * MERGE_K;
            float a = 0.0f;
            for (int k = 0; k < MERGE_K; k += 4) {
                const float4 xa = *(const float4*)&Rows[sus][0][kb + k];
                const float4 pa = *(const float4*)&Rows[sus][1][kb + k];
                a = fmaf(xa.x, pa.x, a);
                a = fmaf(xa.y, pa.y, a);
                a = fmaf(xa.z, pa.z, a);
                a = fmaf(xa.w, pa.w, a);
            }
            part[sus][p] = a;
        }
        __syncthreads();

        if (tid < (int)nsus) {
            const float y = part[tid][0] + part[tid][1];   // exact R9 merge
            float c[TQ_KC];
#pragma unroll
            for (int q = 0; q < TQ_KC; ++q) c[q] = Cent[q];
            int best = 0;
            float bd = fabsf(y - c[0]);
#pragma unroll
            for (int q = 1; q < TQ_KC; ++q) {
                const float d = fabsf(y - c[q]);
                if (d < bd) { bd = d; best = q; }
            }
            const unsigned id = ids[tid];
            OutIdx[(size_t)(id >> 10) * TQ_D + (id & (TQ_D - 1))] = (float)best;
        }
        __syncthreads();
    }
}

// ---------------------------------------------------------------------------
// Kernel 2 (MFMA, proven R15): x_hat = dequant(idx) @ Pi, bf16 MFMA f32-acc.
// ---------------------------------------------------------------------------
__global__ __launch_bounds__(256)
void tq_dq_mfma(const float* __restrict__ IdxF,
                const float* __restrict__ Pi,
                const float* __restrict__ Cent,
                float* __restrict__ Xhat)
{
    __shared__ unsigned short Ys[128][40];
    __shared__ unsigned short Ps[128][40];
    __shared__ unsigned short csb[TQ_KC];

    const int tid  = threadIdx.x;
    const int lane = tid & 63;
    const int wv   = tid >> 6;
    const int m0 = blockIdx.y * 128;
    const int n0 = blockIdx.x * 128;
    const int wr = (wv >> 1) * 64;
    const int wc = (wv & 1) * 64;
    const int l15 = lane & 15;
    const int k8  = (lane >> 4) * 8;

    const int arow = tid >> 1;
    const int acol = (tid & 1) * 16;
    const int bn   = tid & 127;
    const int bkq  = (tid >> 7) * 16;

    const float* aP = IdxF + (size_t)(m0 + arow) * TQ_D + acol;
    const float* bP = Pi + (size_t)bkq * TQ_D + n0 + bn;

    if (tid < TQ_KC) csb[tid] = f2bf(Cent[tid]);

    f32x4 acc[4][4];
#pragma unroll
    for (int i = 0; i < 4; ++i)
#pragma unroll
        for (int j = 0; j < 4; ++j)
#pragma unroll
            for (int r = 0; r < 4; ++r) acc[i][j][r] = 0.0f;

    float4 va[4];
    float  vb[16];
#pragma unroll
    for (int q = 0; q < 4; ++q) va[q] = *(const float4*)(aP + 4 * q);
#pragma unroll
    for (int k = 0; k < 16; ++k) vb[k] = bP[(size_t)k * TQ_D];

    __syncthreads();   // csb ready

#pragma unroll
    for (int q = 0; q < 4; ++q) {
        ushort4 w;
        w.x = csb[(int)va[q].x & 15];
        w.y = csb[(int)va[q].y & 15];
        w.z = csb[(int)va[q].z & 15];
        w.w = csb[(int)va[q].w & 15];
        *(ushort4*)&Ys[arow][acol + 4 * q] = w;
    }
#pragma unroll
    for (int k = 0; k < 16; ++k) Ps[bn][bkq + k] = f2bf(vb[k]);
    __syncthreads();

    for (int kt = 0; kt < 32; ++kt) {
        const bool more = (kt + 1) < 32;
        if (more) {
            const float* ap = aP + (kt + 1) * 32;
            const float* bp = bP + (size_t)(kt + 1) * 32 * TQ_D;
#pragma unroll
            for (int q = 0; q < 4; ++q) va[q] = *(const float4*)(ap + 4 * q);
#pragma unroll
            for (int k = 0; k < 16; ++k) vb[k] = bp[(size_t)k * TQ_D];
        }

        bf16x8 af[4], bfr[4];
#pragma unroll
        for (int i = 0; i < 4; ++i)
            af[i] = *(const bf16x8*)&Ys[wr + i * 16 + l15][k8];
#pragma unroll
        for (int j = 0; j < 4; ++j)
            bfr[j] = *(const bf16x8*)&Ps[wc + j * 16 + l15][k8];

#pragma unroll
        for (int i = 0; i < 4; ++i)
#pragma unroll
            for (int j = 0; j < 4; ++j)
                acc[i][j] = __builtin_amdgcn_mfma_f32_16x16x32_bf16(
                    af[i], bfr[j], acc[i][j], 0, 0, 0);

        if (more) {
            __syncthreads();
#pragma unroll
            for (int q = 0; q < 4; ++q) {
                ushort4 w;
                w.x = csb[(int)va[q].x & 15];
                w.y = csb[(int)va[q].y & 15];
                w.z = csb[(int)va[q].z & 15];
                w.w = csb[(int)va[q].w & 15];
                *(ushort4*)&Ys[arow][acol + 4 * q] = w;
            }
#pragma unroll
            for (int k = 0; k < 16; ++k) Ps[bn][bkq + k] = f2bf(vb[k]);
            __syncthreads();
        }
    }

#pragma unroll
    for (int i = 0; i < 4; ++i)
#pragma unroll
        for (int j = 0; j < 4; ++j)
#pragma unroll
            for (int r = 0; r < 4; ++r) {
                const int row = wr + i * 16 + (lane >> 4) * 4 + r;
                const int col = wc + j * 16 + l15;
                Xhat[(size_t)(m0 + row) * TQ_D + n0 + col] = acc[i][j][r];
            }
}

// ---------------------------------------------------------------------------
extern "C" void kernel_launch(void* const* d_in, const int* in_sizes, int n_in,
                              void* d_out, int out_size, void* d_ws, size_t ws_size,
                              hipStream_t stream)
{
    const float* x    = (const float*)d_in[0];   // [N, 1024]
    const float* Pi   = (const float*)d_in[1];   // [1024, 1024]
    const float* cent = (const float*)d_in[2];   // [16]
    float* out = (float*)d_out;

    const int ND = in_sizes[0];      // N * 1024
    const int DD = in_sizes[1];      // 1024 * 1024
    const int N  = ND / TQ_D;        // 4096

    float* xhat = out;               // output 0 (scratch: counter+list pre-K2)
    float* oidx = out + ND;          // output 1: indices as float

    unsigned* counter = (unsigned*)xhat;
    unsigned* list    = (unsigned*)xhat + 16;
    const unsigned cap = (unsigned)(ND - 16);

    hipMemsetAsync(counter, 0, 4, stream);   // zero suspect counter

    dim3 grid(TQ_D / 128, N / 128);  // (8, 32) = 256 blocks

    const size_t wsNeed = (size_t)ND * 4 + (size_t)DD * 4;  // Xh+Xl+Ph+Pl bf16
    if (ws_size >= wsNeed) {
        unsigned short* Xh = (unsigned short*)d_ws;
        unsigned short* Xl = Xh + ND;
        unsigned short* Ph = Xl + ND;
        unsigned short* Pl = Ph + DD;
        tq_split<<<2048, 256, 0, stream>>>(x, Xh, Xl, ND / 4);
        tq_split<<<1024, 256, 0, stream>>>(Pi, Ph, Pl, DD / 4);
        tq_rq_mfma_pre<<<grid, 256, 0, stream>>>(Xh, Xl, Ph, Pl, cent, oidx,
                                                 counter, list, cap);
    } else {
        tq_rq_mfma_fused<<<grid, 256, 0, stream>>>(x, Pi, cent, oidx,
                                                   counter, list, cap);
    }

    // Dense exact recompute of suspects (R9 realization), LDS-staged.
    tq_fixup_lds<<<1024, 256, 0, stream>>>(x, Pi, cent, oidx, counter, list, cap);

    // Dequant + unrotate (MFMA) -> xhat (overwrites scratch).
    tq_dq_mfma<<<grid, 256, 0, stream>>>(oidx, Pi, cent, xhat);
}

// Round 22
// 169.929 us; speedup vs baseline: 1.4158x; 1.4158x over previous
//
#include <hip/hip_runtime.h>
#include <hip/hip_bf16.h>

#define TQ_D   1024
#define TQ_KC  16
#define MERGE_K 512          // OpenBLAS KC-panel boundary (proven R9)
#define TQ_TOL  2.0e-4f      // ~100 sigma of 4-term MFMA vs serial-f32 error
#define LCAP    1024         // per-block LDS suspect-list capacity

typedef __attribute__((ext_vector_type(8))) short bf16x8;
typedef __attribute__((ext_vector_type(4))) float f32x4;

__device__ __forceinline__ unsigned short f2bf(float f) {
    union { __hip_bfloat16 h; unsigned short s; } u;
    u.h = __float2bfloat16(f);
    return u.s;
}
__device__ __forceinline__ float bf2f(unsigned short s) {
    union { unsigned int u; float f; } v;
    v.u = (unsigned int)s << 16;
    return v.f;
}

// ---------------------------------------------------------------------------
// K1-MFMA (4-term): y = x @ Pi^T via bf16 hi/lo split with ALL FOUR terms
// (xh*ph + xl*ph + xh*pl + xl*pl), f32 MFMA accum -> |y - y_ref| ~ 2e-6 sigma,
// worst case < 1e-4. Literal f32 argmin; suspects (dist < 2e-4) aggregated
// per-block in LDS, one global atomicAdd per block (R20-proven).
// ---------------------------------------------------------------------------
__global__ __launch_bounds__(256)
void tq_rq_mfma(const float* __restrict__ X,
                const float* __restrict__ Pi,
                const float* __restrict__ Cent,
                float* __restrict__ OutIdx,
                unsigned* __restrict__ Counter,
                unsigned* __restrict__ List,
                unsigned cap)
{
    __shared__ unsigned short XhS[128][40];
    __shared__ unsigned short XlS[128][40];
    __shared__ unsigned short PhS[128][40];
    __shared__ unsigned short PlS[128][40];
    __shared__ unsigned lcount;
    __shared__ unsigned gbase;
    __shared__ unsigned llist[LCAP];

    const int tid  = threadIdx.x;
    const int lane = tid & 63;
    const int wv   = tid >> 6;
    const int m0 = blockIdx.y * 128;
    const int n0 = blockIdx.x * 128;
    const int wr = (wv >> 1) * 64;
    const int wc = (wv & 1) * 64;
    const int l15 = lane & 15;
    const int k8  = (lane >> 4) * 8;

    const int srow = tid >> 1;
    const int scol = (tid & 1) * 16;

    const float* aP = X  + (size_t)(m0 + srow) * TQ_D + scol;
    const float* bP = Pi + (size_t)(n0 + srow) * TQ_D + scol;

    if (tid == 0) lcount = 0;

    f32x4 acc[4][4];
#pragma unroll
    for (int i = 0; i < 4; ++i)
#pragma unroll
        for (int j = 0; j < 4; ++j)
#pragma unroll
            for (int r = 0; r < 4; ++r) acc[i][j][r] = 0.0f;

    float4 va[4], vb[4];
#pragma unroll
    for (int q = 0; q < 4; ++q) {
        va[q] = *(const float4*)(aP + 4 * q);
        vb[q] = *(const float4*)(bP + 4 * q);
    }

#pragma unroll
    for (int q = 0; q < 4; ++q) {
        ushort4 ah, al, bh, bl;
        const float* fa = (const float*)&va[q];
        const float* fb = (const float*)&vb[q];
        ah.x = f2bf(fa[0]); al.x = f2bf(fa[0] - bf2f(ah.x));
        ah.y = f2bf(fa[1]); al.y = f2bf(fa[1] - bf2f(ah.y));
        ah.z = f2bf(fa[2]); al.z = f2bf(fa[2] - bf2f(ah.z));
        ah.w = f2bf(fa[3]); al.w = f2bf(fa[3] - bf2f(ah.w));
        bh.x = f2bf(fb[0]); bl.x = f2bf(fb[0] - bf2f(bh.x));
        bh.y = f2bf(fb[1]); bl.y = f2bf(fb[1] - bf2f(bh.y));
        bh.z = f2bf(fb[2]); bl.z = f2bf(fb[2] - bf2f(bh.z));
        bh.w = f2bf(fb[3]); bl.w = f2bf(fb[3] - bf2f(bh.w));
        *(ushort4*)&XhS[srow][scol + 4 * q] = ah;
        *(ushort4*)&XlS[srow][scol + 4 * q] = al;
        *(ushort4*)&PhS[srow][scol + 4 * q] = bh;
        *(ushort4*)&PlS[srow][scol + 4 * q] = bl;
    }
    __syncthreads();   // also covers lcount init

    for (int kt = 0; kt < 32; ++kt) {
        const bool more = (kt + 1) < 32;
        if (more) {
            const float* ap = aP + (kt + 1) * 32;
            const float* bp = bP + (kt + 1) * 32;
#pragma unroll
            for (int q = 0; q < 4; ++q) {
                va[q] = *(const float4*)(ap + 4 * q);
                vb[q] = *(const float4*)(bp + 4 * q);
            }
        }

        bf16x8 afh[4], afl[4], bfh[4], bfl[4];
#pragma unroll
        for (int i = 0; i < 4; ++i) {
            afh[i] = *(const bf16x8*)&XhS[wr + i * 16 + l15][k8];
            afl[i] = *(const bf16x8*)&XlS[wr + i * 16 + l15][k8];
        }
#pragma unroll
        for (int j = 0; j < 4; ++j) {
            bfh[j] = *(const bf16x8*)&PhS[wc + j * 16 + l15][k8];
            bfl[j] = *(const bf16x8*)&PlS[wc + j * 16 + l15][k8];
        }

#pragma unroll
        for (int i = 0; i < 4; ++i)
#pragma unroll
            for (int j = 0; j < 4; ++j) {
                acc[i][j] = __builtin_amdgcn_mfma_f32_16x16x32_bf16(
                    afh[i], bfh[j], acc[i][j], 0, 0, 0);
                acc[i][j] = __builtin_amdgcn_mfma_f32_16x16x32_bf16(
                    afl[i], bfh[j], acc[i][j], 0, 0, 0);
                acc[i][j] = __builtin_amdgcn_mfma_f32_16x16x32_bf16(
                    afh[i], bfl[j], acc[i][j], 0, 0, 0);
                acc[i][j] = __builtin_amdgcn_mfma_f32_16x16x32_bf16(
                    afl[i], bfl[j], acc[i][j], 0, 0, 0);   // 4th term
            }

        if (more) {
            __syncthreads();
#pragma unroll
            for (int q = 0; q < 4; ++q) {
                ushort4 ah, al, bh, bl;
                const float* fa = (const float*)&va[q];
                const float* fb = (const float*)&vb[q];
                ah.x = f2bf(fa[0]); al.x = f2bf(fa[0] - bf2f(ah.x));
                ah.y = f2bf(fa[1]); al.y = f2bf(fa[1] - bf2f(ah.y));
                ah.z = f2bf(fa[2]); al.z = f2bf(fa[2] - bf2f(ah.z));
                ah.w = f2bf(fa[3]); al.w = f2bf(fa[3] - bf2f(ah.w));
                bh.x = f2bf(fb[0]); bl.x = f2bf(fb[0] - bf2f(bh.x));
                bh.y = f2bf(fb[1]); bl.y = f2bf(fb[1] - bf2f(bh.y));
                bh.z = f2bf(fb[2]); bl.z = f2bf(fb[2] - bf2f(bh.z));
                bh.w = f2bf(fb[3]); bl.w = f2bf(fb[3] - bf2f(bh.w));
                *(ushort4*)&XhS[srow][scol + 4 * q] = ah;
                *(ushort4*)&XlS[srow][scol + 4 * q] = al;
                *(ushort4*)&PhS[srow][scol + 4 * q] = bh;
                *(ushort4*)&PlS[srow][scol + 4 * q] = bl;
            }
            __syncthreads();
        }
    }

    float c[TQ_KC];
#pragma unroll
    for (int q = 0; q < TQ_KC; ++q) c[q] = Cent[q];

#pragma unroll
    for (int i = 0; i < 4; ++i)
#pragma unroll
        for (int j = 0; j < 4; ++j)
#pragma unroll
            for (int r = 0; r < 4; ++r) {
                const int row = m0 + wr + i * 16 + (lane >> 4) * 4 + r;
                const int col = n0 + wc + j * 16 + l15;
                const float y = acc[i][j][r];
                int best = 0;
                float bd = fabsf(y - c[0]);
#pragma unroll
                for (int q = 1; q < TQ_KC; ++q) {
                    const float d = fabsf(y - c[q]);
                    if (d < bd) { bd = d; best = q; }
                }
                float dist = 1e30f;
#pragma unroll
                for (int q = 0; q < TQ_KC - 1; ++q) {
                    const float mid = 0.5f * (c[q] + c[q + 1]);
                    dist = fminf(dist, fabsf(y - mid));
                }
                if (dist < TQ_TOL) {
                    const unsigned id = ((unsigned)row << 10) | (unsigned)col;
                    const unsigned ls = atomicAdd(&lcount, 1u);
                    if (ls < LCAP) {
                        llist[ls] = id;
                    } else {
                        const unsigned gs = atomicAdd(Counter, 1u);
                        if (gs < cap) List[gs] = id;
                    }
                }
                OutIdx[(size_t)row * TQ_D + col] = (float)best;
            }

    __syncthreads();
    if (tid == 0) {
        const unsigned cnt = min(lcount, (unsigned)LCAP);
        gbase = (cnt > 0) ? atomicAdd(Counter, cnt) : 0u;
    }
    __syncthreads();
    const unsigned cnt = min(lcount, (unsigned)LCAP);
    for (unsigned s = tid; s < cnt; s += 256) {
        const unsigned g = gbase + s;
        if (g < cap) List[g] = llist[s];
    }
}

// ---------------------------------------------------------------------------
// Fixup (LDS-staged, proven R21-correct): 8 suspects/block; cooperative
// 64KB row staging; two independent 512-wide serial panel chains per suspect
// (exact R9 realization), merge a1+a2, literal argmin.
// ---------------------------------------------------------------------------
__global__ __launch_bounds__(256)
void tq_fixup_lds(const float* __restrict__ X,
                  const float* __restrict__ Pi,
                  const float* __restrict__ Cent,
                  float* __restrict__ OutIdx,
                  const unsigned* __restrict__ Counter,
                  const unsigned* __restrict__ List,
                  unsigned cap)
{
    __shared__ float Rows[8][2][1024];   // [suspect][0=X,1=Pi][k]
    __shared__ float part[8][2];
    __shared__ unsigned ids[8];

    const int tid = threadIdx.x;
    const unsigned count = min(*Counter, cap);

    for (unsigned base = blockIdx.x * 8; base < count; base += gridDim.x * 8) {
        const unsigned nsus = min(8u, count - base);

        if (tid < 8) ids[tid] = (tid < nsus) ? List[base + tid] : 0u;
        __syncthreads();

#pragma unroll
        for (int q = 0; q < 16; ++q) {
            const int lin = q * 256 + tid;
            const int sus = lin >> 9;            // 512 float4 per suspect
            const int rowsel = (lin >> 8) & 1;   // 0 = X row, 1 = Pi row
            const int f4 = lin & 255;
            if ((unsigned)sus < nsus) {
                const unsigned id = ids[sus];
                const int m = id >> 10;
                const int n = id & (TQ_D - 1);
                const float* src = rowsel ? (Pi + (size_t)n * TQ_D)
                                          : (X + (size_t)m * TQ_D);
                *(float4*)&Rows[sus][rowsel][f4 * 4] =
                    *(const float4*)(src + f4 * 4);
            }
        }
        __syncthreads();

        if (tid < 16 && (unsigned)(tid >> 1) < nsus) {
            const int sus = tid >> 1;
            const int p = tid & 1;
            const int kb = p * MERGE_K;
            float a = 0.0f;
            for (int k = 0; k < MERGE_K; k += 4) {
                const float4 xa = *(const float4*)&Rows[sus][0][kb + k];
                const float4 pa = *(const float4*)&Rows[sus][1][kb + k];
                a = fmaf(xa.x, pa.x, a);
                a = fmaf(xa.y, pa.y, a);
                a = fmaf(xa.z, pa.z, a);
                a = fmaf(xa.w, pa.w, a);
            }
            part[sus][p] = a;
        }
        __syncthreads();

        if (tid < (int)nsus) {
            const float y = part[tid][0] + part[tid][1];   // exact R9 merge
            float c[TQ_KC];
#pragma unroll
            for (int q = 0; q < TQ_KC; ++q) c[q] = Cent[q];
            int best = 0;
            float bd = fabsf(y - c[0]);
#pragma unroll
            for (int q = 1; q < TQ_KC; ++q) {
                const float d = fabsf(y - c[q]);
                if (d < bd) { bd = d; best = q; }
            }
            const unsigned id = ids[tid];
            OutIdx[(size_t)(id >> 10) * TQ_D + (id & (TQ_D - 1))] = (float)best;
        }
        __syncthreads();
    }
}

// ---------------------------------------------------------------------------
// Kernel 2 (MFMA, proven R15): x_hat = dequant(idx) @ Pi, bf16 MFMA f32-acc.
// ---------------------------------------------------------------------------
__global__ __launch_bounds__(256)
void tq_dq_mfma(const float* __restrict__ IdxF,
                const float* __restrict__ Pi,
                const float* __restrict__ Cent,
                float* __restrict__ Xhat)
{
    __shared__ unsigned short Ys[128][40];
    __shared__ unsigned short Ps[128][40];
    __shared__ unsigned short csb[TQ_KC];

    const int tid  = threadIdx.x;
    const int lane = tid & 63;
    const int wv   = tid >> 6;
    const int m0 = blockIdx.y * 128;
    const int n0 = blockIdx.x * 128;
    const int wr = (wv >> 1) * 64;
    const int wc = (wv & 1) * 64;
    const int l15 = lane & 15;
    const int k8  = (lane >> 4) * 8;

    const int arow = tid >> 1;
    const int acol = (tid & 1) * 16;
    const int bn   = tid & 127;
    const int bkq  = (tid >> 7) * 16;

    const float* aP = IdxF + (size_t)(m0 + arow) * TQ_D + acol;
    const float* bP = Pi + (size_t)bkq * TQ_D + n0 + bn;

    if (tid < TQ_KC) csb[tid] = f2bf(Cent[tid]);

    f32x4 acc[4][4];
#pragma unroll
    for (int i = 0; i < 4; ++i)
#pragma unroll
        for (int j = 0; j < 4; ++j)
#pragma unroll
            for (int r = 0; r < 4; ++r) acc[i][j][r] = 0.0f;

    float4 va[4];
    float  vb[16];
#pragma unroll
    for (int q = 0; q < 4; ++q) va[q] = *(const float4*)(aP + 4 * q);
#pragma unroll
    for (int k = 0; k < 16; ++k) vb[k] = bP[(size_t)k * TQ_D];

    __syncthreads();   // csb ready

#pragma unroll
    for (int q = 0; q < 4; ++q) {
        ushort4 w;
        w.x = csb[(int)va[q].x & 15];
        w.y = csb[(int)va[q].y & 15];
        w.z = csb[(int)va[q].z & 15];
        w.w = csb[(int)va[q].w & 15];
        *(ushort4*)&Ys[arow][acol + 4 * q] = w;
    }
#pragma unroll
    for (int k = 0; k < 16; ++k) Ps[bn][bkq + k] = f2bf(vb[k]);
    __syncthreads();

    for (int kt = 0; kt < 32; ++kt) {
        const bool more = (kt + 1) < 32;
        if (more) {
            const float* ap = aP + (kt + 1) * 32;
            const float* bp = bP + (size_t)(kt + 1) * 32 * TQ_D;
#pragma unroll
            for (int q = 0; q < 4; ++q) va[q] = *(const float4*)(ap + 4 * q);
#pragma unroll
            for (int k = 0; k < 16; ++k) vb[k] = bp[(size_t)k * TQ_D];
        }

        bf16x8 af[4], bfr[4];
#pragma unroll
        for (int i = 0; i < 4; ++i)
            af[i] = *(const bf16x8*)&Ys[wr + i * 16 + l15][k8];
#pragma unroll
        for (int j = 0; j < 4; ++j)
            bfr[j] = *(const bf16x8*)&Ps[wc + j * 16 + l15][k8];

#pragma unroll
        for (int i = 0; i < 4; ++i)
#pragma unroll
            for (int j = 0; j < 4; ++j)
                acc[i][j] = __builtin_amdgcn_mfma_f32_16x16x32_bf16(
                    af[i], bfr[j], acc[i][j], 0, 0, 0);

        if (more) {
            __syncthreads();
#pragma unroll
            for (int q = 0; q < 4; ++q) {
                ushort4 w;
                w.x = csb[(int)va[q].x & 15];
                w.y = csb[(int)va[q].y & 15];
                w.z = csb[(int)va[q].z & 15];
                w.w = csb[(int)va[q].w & 15];
                *(ushort4*)&Ys[arow][acol + 4 * q] = w;
            }
#pragma unroll
            for (int k = 0; k < 16; ++k) Ps[bn][bkq + k] = f2bf(vb[k]);
            __syncthreads();
        }
    }

#pragma unroll
    for (int i = 0; i < 4; ++i)
#pragma unroll
        for (int j = 0; j < 4; ++j)
#pragma unroll
            for (int r = 0; r < 4; ++r) {
                const int row = wr + i * 16 + (lane >> 4) * 4 + r;
                const int col = wc + j * 16 + l15;
                Xhat[(size_t)(m0 + row) * TQ_D + n0 + col] = acc[i][j][r];
            }
}

// ---------------------------------------------------------------------------
extern "C" void kernel_launch(void* const* d_in, const int* in_sizes, int n_in,
                              void* d_out, int out_size, void* d_ws, size_t ws_size,
                              hipStream_t stream)
{
    const float* x    = (const float*)d_in[0];   // [N, 1024]
    const float* Pi   = (const float*)d_in[1];   // [1024, 1024]
    const float* cent = (const float*)d_in[2];   // [16]
    float* out = (float*)d_out;

    const int ND = in_sizes[0];      // N * 1024
    const int N  = ND / TQ_D;        // 4096

    float* xhat = out;               // output 0 (scratch: counter+list pre-K2)
    float* oidx = out + ND;          // output 1: indices as float

    unsigned* counter = (unsigned*)xhat;
    unsigned* list    = (unsigned*)xhat + 16;
    const unsigned cap = (unsigned)(ND - 16);

    hipMemsetAsync(counter, 0, 4, stream);   // zero suspect counter

    dim3 grid(TQ_D / 128, N / 128);  // (8, 32) = 256 blocks

    // Pass 1: 4-term MFMA rotate+quantize -> indices + compact suspects.
    tq_rq_mfma<<<grid, 256, 0, stream>>>(x, Pi, cent, oidx, counter, list, cap);

    // Pass 2: exact recompute of suspects (R9 realization), LDS-staged.
    tq_fixup_lds<<<1024, 256, 0, stream>>>(x, Pi, cent, oidx, counter, list, cap);

    // Pass 3: dequant + unrotate (MFMA) -> xhat (overwrites scratch).
    tq_dq_mfma<<<grid, 256, 0, stream>>>(oidx, Pi, cent, xhat);
}

// Round 23
// 143.685 us; speedup vs baseline: 1.6743x; 1.1826x over previous
//
#include <hip/hip_runtime.h>
#include <hip/hip_bf16.h>

#define TQ_D   1024
#define TQ_KC  16
#define MERGE_K 512          // OpenBLAS KC-panel boundary (proven R9)
#define TQ_TOL  2.0e-4f      // ~100 sigma of 4-term MFMA vs serial-f32 error
#define LCAP    1024         // per-block LDS suspect-list capacity

typedef __attribute__((ext_vector_type(8))) short bf16x8;
typedef __attribute__((ext_vector_type(4))) float f32x4;

__device__ __forceinline__ unsigned short f2bf(float f) {
    union { __hip_bfloat16 h; unsigned short s; } u;
    u.h = __float2bfloat16(f);
    return u.s;
}
__device__ __forceinline__ float bf2f(unsigned short s) {
    union { unsigned int u; float f; } v;
    v.u = (unsigned int)s << 16;
    return v.f;
}

// ---------------------------------------------------------------------------
// K1-MFMA (4-term, 8-wave): y = x @ Pi^T via bf16 hi/lo split with all four
// terms, f32 MFMA accum. 512 threads = 8 waves (2 rows x 4 cols of 64x32
// wave-tiles) so staging VALU of one wave overlaps MFMA of another (R22 had
// 4 barrier-locked waves/CU -> MfmaUtil 12.7%). Literal f32 argmin; suspects
// (dist < TOL) aggregated per-block in LDS, one global atomicAdd per block.
// ---------------------------------------------------------------------------
__global__ __launch_bounds__(512)
void tq_rq_mfma(const float* __restrict__ X,
                const float* __restrict__ Pi,
                const float* __restrict__ Cent,
                float* __restrict__ OutIdx,
                unsigned* __restrict__ Counter,
                unsigned* __restrict__ List,
                unsigned cap)
{
    __shared__ unsigned short XhS[128][40];
    __shared__ unsigned short XlS[128][40];
    __shared__ unsigned short PhS[128][40];
    __shared__ unsigned short PlS[128][40];
    __shared__ unsigned lcount;
    __shared__ unsigned gbase;
    __shared__ unsigned llist[LCAP];

    const int tid  = threadIdx.x;
    const int lane = tid & 63;
    const int wv   = tid >> 6;          // 0..7
    const int m0 = blockIdx.y * 128;
    const int n0 = blockIdx.x * 128;
    const int wr = (wv >> 2) * 64;      // wave row origin (0 or 64)
    const int wc = (wv & 3) * 32;       // wave col origin (0/32/64/96)
    const int l15 = lane & 15;
    const int k8  = (lane >> 4) * 8;

    // staging: 128 rows x 32 k per matrix; each thread 8 A + 8 B floats
    const int srow = tid >> 2;          // 0..127
    const int scol = (tid & 3) * 8;     // 0/8/16/24

    const float* aP = X  + (size_t)(m0 + srow) * TQ_D + scol;
    const float* bP = Pi + (size_t)(n0 + srow) * TQ_D + scol;

    if (tid == 0) lcount = 0;

    f32x4 acc[4][2];
#pragma unroll
    for (int i = 0; i < 4; ++i)
#pragma unroll
        for (int j = 0; j < 2; ++j)
#pragma unroll
            for (int r = 0; r < 4; ++r) acc[i][j][r] = 0.0f;

    float4 va[2], vb[2];
#pragma unroll
    for (int q = 0; q < 2; ++q) {
        va[q] = *(const float4*)(aP + 4 * q);
        vb[q] = *(const float4*)(bP + 4 * q);
    }

#pragma unroll
    for (int q = 0; q < 2; ++q) {
        ushort4 ah, al, bh, bl;
        const float* fa = (const float*)&va[q];
        const float* fb = (const float*)&vb[q];
        ah.x = f2bf(fa[0]); al.x = f2bf(fa[0] - bf2f(ah.x));
        ah.y = f2bf(fa[1]); al.y = f2bf(fa[1] - bf2f(ah.y));
        ah.z = f2bf(fa[2]); al.z = f2bf(fa[2] - bf2f(ah.z));
        ah.w = f2bf(fa[3]); al.w = f2bf(fa[3] - bf2f(ah.w));
        bh.x = f2bf(fb[0]); bl.x = f2bf(fb[0] - bf2f(bh.x));
        bh.y = f2bf(fb[1]); bl.y = f2bf(fb[1] - bf2f(bh.y));
        bh.z = f2bf(fb[2]); bl.z = f2bf(fb[2] - bf2f(bh.z));
        bh.w = f2bf(fb[3]); bl.w = f2bf(fb[3] - bf2f(bh.w));
        *(ushort4*)&XhS[srow][scol + 4 * q] = ah;
        *(ushort4*)&XlS[srow][scol + 4 * q] = al;
        *(ushort4*)&PhS[srow][scol + 4 * q] = bh;
        *(ushort4*)&PlS[srow][scol + 4 * q] = bl;
    }
    __syncthreads();   // also covers lcount init

    for (int kt = 0; kt < 32; ++kt) {
        const bool more = (kt + 1) < 32;
        if (more) {
            const float* ap = aP + (kt + 1) * 32;
            const float* bp = bP + (kt + 1) * 32;
#pragma unroll
            for (int q = 0; q < 2; ++q) {
                va[q] = *(const float4*)(ap + 4 * q);
                vb[q] = *(const float4*)(bp + 4 * q);
            }
        }

        bf16x8 afh[4], afl[4], bfh[2], bfl[2];
#pragma unroll
        for (int i = 0; i < 4; ++i) {
            afh[i] = *(const bf16x8*)&XhS[wr + i * 16 + l15][k8];
            afl[i] = *(const bf16x8*)&XlS[wr + i * 16 + l15][k8];
        }
#pragma unroll
        for (int j = 0; j < 2; ++j) {
            bfh[j] = *(const bf16x8*)&PhS[wc + j * 16 + l15][k8];
            bfl[j] = *(const bf16x8*)&PlS[wc + j * 16 + l15][k8];
        }

#pragma unroll
        for (int i = 0; i < 4; ++i)
#pragma unroll
            for (int j = 0; j < 2; ++j) {
                acc[i][j] = __builtin_amdgcn_mfma_f32_16x16x32_bf16(
                    afh[i], bfh[j], acc[i][j], 0, 0, 0);
                acc[i][j] = __builtin_amdgcn_mfma_f32_16x16x32_bf16(
                    afl[i], bfh[j], acc[i][j], 0, 0, 0);
                acc[i][j] = __builtin_amdgcn_mfma_f32_16x16x32_bf16(
                    afh[i], bfl[j], acc[i][j], 0, 0, 0);
                acc[i][j] = __builtin_amdgcn_mfma_f32_16x16x32_bf16(
                    afl[i], bfl[j], acc[i][j], 0, 0, 0);
            }

        if (more) {
            __syncthreads();
#pragma unroll
            for (int q = 0; q < 2; ++q) {
                ushort4 ah, al, bh, bl;
                const float* fa = (const float*)&va[q];
                const float* fb = (const float*)&vb[q];
                ah.x = f2bf(fa[0]); al.x = f2bf(fa[0] - bf2f(ah.x));
                ah.y = f2bf(fa[1]); al.y = f2bf(fa[1] - bf2f(ah.y));
                ah.z = f2bf(fa[2]); al.z = f2bf(fa[2] - bf2f(ah.z));
                ah.w = f2bf(fa[3]); al.w = f2bf(fa[3] - bf2f(ah.w));
                bh.x = f2bf(fb[0]); bl.x = f2bf(fb[0] - bf2f(bh.x));
                bh.y = f2bf(fb[1]); bl.y = f2bf(fb[1] - bf2f(bh.y));
                bh.z = f2bf(fb[2]); bl.z = f2bf(fb[2] - bf2f(bh.z));
                bh.w = f2bf(fb[3]); bl.w = f2bf(fb[3] - bf2f(bh.w));
                *(ushort4*)&XhS[srow][scol + 4 * q] = ah;
                *(ushort4*)&XlS[srow][scol + 4 * q] = al;
                *(ushort4*)&PhS[srow][scol + 4 * q] = bh;
                *(ushort4*)&PlS[srow][scol + 4 * q] = bl;
            }
            __syncthreads();
        }
    }

    float c[TQ_KC];
#pragma unroll
    for (int q = 0; q < TQ_KC; ++q) c[q] = Cent[q];

#pragma unroll
    for (int i = 0; i < 4; ++i)
#pragma unroll
        for (int j = 0; j < 2; ++j)
#pragma unroll
            for (int r = 0; r < 4; ++r) {
                const int row = m0 + wr + i * 16 + (lane >> 4) * 4 + r;
                const int col = n0 + wc + j * 16 + l15;
                const float y = acc[i][j][r];
                int best = 0;
                float bd = fabsf(y - c[0]);
#pragma unroll
                for (int q = 1; q < TQ_KC; ++q) {
                    const float d = fabsf(y - c[q]);
                    if (d < bd) { bd = d; best = q; }
                }
                float dist = 1e30f;
#pragma unroll
                for (int q = 0; q < TQ_KC - 1; ++q) {
                    const float mid = 0.5f * (c[q] + c[q + 1]);
                    dist = fminf(dist, fabsf(y - mid));
                }
                if (dist < TQ_TOL) {
                    const unsigned id = ((unsigned)row << 10) | (unsigned)col;
                    const unsigned ls = atomicAdd(&lcount, 1u);
                    if (ls < LCAP) {
                        llist[ls] = id;
                    } else {
                        const unsigned gs = atomicAdd(Counter, 1u);
                        if (gs < cap) List[gs] = id;
                    }
                }
                OutIdx[(size_t)row * TQ_D + col] = (float)best;
            }

    __syncthreads();
    if (tid == 0) {
        const unsigned cnt = min(lcount, (unsigned)LCAP);
        gbase = (cnt > 0) ? atomicAdd(Counter, cnt) : 0u;
    }
    __syncthreads();
    const unsigned cnt = min(lcount, (unsigned)LCAP);
    for (unsigned s = tid; s < cnt; s += 512) {
        const unsigned g = gbase + s;
        if (g < cap) List[g] = llist[s];
    }
}

// ---------------------------------------------------------------------------
// Fixup (LDS-staged, proven R21/R22): 8 suspects/block; cooperative 64KB row
// staging; two independent 512-wide serial panel chains per suspect (exact
// R9 realization), merge a1+a2, literal argmin.
// ---------------------------------------------------------------------------
__global__ __launch_bounds__(256)
void tq_fixup_lds(const float* __restrict__ X,
                  const float* __restrict__ Pi,
                  const float* __restrict__ Cent,
                  float* __restrict__ OutIdx,
                  const unsigned* __restrict__ Counter,
                  const unsigned* __restrict__ List,
                  unsigned cap)
{
    __shared__ float Rows[8][2][1024];   // [suspect][0=X,1=Pi][k]
    __shared__ float part[8][2];
    __shared__ unsigned ids[8];

    const int tid = threadIdx.x;
    const unsigned count = min(*Counter, cap);

    for (unsigned base = blockIdx.x * 8; base < count; base += gridDim.x * 8) {
        const unsigned nsus = min(8u, count - base);

        if (tid < 8) ids[tid] = (tid < nsus) ? List[base + tid] : 0u;
        __syncthreads();

#pragma unroll
        for (int q = 0; q < 16; ++q) {
            const int lin = q * 256 + tid;
            const int sus = lin >> 9;            // 512 float4 per suspect
            const int rowsel = (lin >> 8) & 1;   // 0 = X row, 1 = Pi row
            const int f4 = lin & 255;
            if ((unsigned)sus < nsus) {
                const unsigned id = ids[sus];
                const int m = id >> 10;
                const int n = id & (TQ_D - 1);
                const float* src = rowsel ? (Pi + (size_t)n * TQ_D)
                                          : (X + (size_t)m * TQ_D);
                *(float4*)&Rows[sus][rowsel][f4 * 4] =
                    *(const float4*)(src + f4 * 4);
            }
        }
        __syncthreads();

        if (tid < 16 && (unsigned)(tid >> 1) < nsus) {
            const int sus = tid >> 1;
            const int p = tid & 1;
            const int kb = p * MERGE_K;
            float a = 0.0f;
            for (int k = 0; k < MERGE_K; k += 4) {
                const float4 xa = *(const float4*)&Rows[sus][0][kb + k];
                const float4 pa = *(const float4*)&Rows[sus][1][kb + k];
                a = fmaf(xa.x, pa.x, a);
                a = fmaf(xa.y, pa.y, a);
                a = fmaf(xa.z, pa.z, a);
                a = fmaf(xa.w, pa.w, a);
            }
            part[sus][p] = a;
        }
        __syncthreads();

        if (tid < (int)nsus) {
            const float y = part[tid][0] + part[tid][1];   // exact R9 merge
            float c[TQ_KC];
#pragma unroll
            for (int q = 0; q < TQ_KC; ++q) c[q] = Cent[q];
            int best = 0;
            float bd = fabsf(y - c[0]);
#pragma unroll
            for (int q = 1; q < TQ_KC; ++q) {
                const float d = fabsf(y - c[q]);
                if (d < bd) { bd = d; best = q; }
            }
            const unsigned id = ids[tid];
            OutIdx[(size_t)(id >> 10) * TQ_D + (id & (TQ_D - 1))] = (float)best;
        }
        __syncthreads();
    }
}

// ---------------------------------------------------------------------------
// Kernel 2 (MFMA, proven R15): x_hat = dequant(idx) @ Pi, bf16 MFMA f32-acc.
// ---------------------------------------------------------------------------
__global__ __launch_bounds__(256)
void tq_dq_mfma(const float* __restrict__ IdxF,
                const float* __restrict__ Pi,
                const float* __restrict__ Cent,
                float* __restrict__ Xhat)
{
    __shared__ unsigned short Ys[128][40];
    __shared__ unsigned short Ps[128][40];
    __shared__ unsigned short csb[TQ_KC];

    const int tid  = threadIdx.x;
    const int lane = tid & 63;
    const int wv   = tid >> 6;
    const int m0 = blockIdx.y * 128;
    const int n0 = blockIdx.x * 128;
    const int wr = (wv >> 1) * 64;
    const int wc = (wv & 1) * 64;
    const int l15 = lane & 15;
    const int k8  = (lane >> 4) * 8;

    const int arow = tid >> 1;
    const int acol = (tid & 1) * 16;
    const int bn   = tid & 127;
    const int bkq  = (tid >> 7) * 16;

    const float* aP = IdxF + (size_t)(m0 + arow) * TQ_D + acol;
    const float* bP = Pi + (size_t)bkq * TQ_D + n0 + bn;

    if (tid < TQ_KC) csb[tid] = f2bf(Cent[tid]);

    f32x4 acc[4][4];
#pragma unroll
    for (int i = 0; i < 4; ++i)
#pragma unroll
        for (int j = 0; j < 4; ++j)
#pragma unroll
            for (int r = 0; r < 4; ++r) acc[i][j][r] = 0.0f;

    float4 va[4];
    float  vb[16];
#pragma unroll
    for (int q = 0; q < 4; ++q) va[q] = *(const float4*)(aP + 4 * q);
#pragma unroll
    for (int k = 0; k < 16; ++k) vb[k] = bP[(size_t)k * TQ_D];

    __syncthreads();   // csb ready

#pragma unroll
    for (int q = 0; q < 4; ++q) {
        ushort4 w;
        w.x = csb[(int)va[q].x & 15];
        w.y = csb[(int)va[q].y & 15];
        w.z = csb[(int)va[q].z & 15];
        w.w = csb[(int)va[q].w & 15];
        *(ushort4*)&Ys[arow][acol + 4 * q] = w;
    }
#pragma unroll
    for (int k = 0; k < 16; ++k) Ps[bn][bkq + k] = f2bf(vb[k]);
    __syncthreads();

    for (int kt = 0; kt < 32; ++kt) {
        const bool more = (kt + 1) < 32;
        if (more) {
            const float* ap = aP + (kt + 1) * 32;
            const float* bp = bP + (size_t)(kt + 1) * 32 * TQ_D;
#pragma unroll
            for (int q = 0; q < 4; ++q) va[q] = *(const float4*)(ap + 4 * q);
#pragma unroll
            for (int k = 0; k < 16; ++k) vb[k] = bp[(size_t)k * TQ_D];
        }

        bf16x8 af[4], bfr[4];
#pragma unroll
        for (int i = 0; i < 4; ++i)
            af[i] = *(const bf16x8*)&Ys[wr + i * 16 + l15][k8];
#pragma unroll
        for (int j = 0; j < 4; ++j)
            bfr[j] = *(const bf16x8*)&Ps[wc + j * 16 + l15][k8];

#pragma unroll
        for (int i = 0; i < 4; ++i)
#pragma unroll
            for (int j = 0; j < 4; ++j)
                acc[i][j] = __builtin_amdgcn_mfma_f32_16x16x32_bf16(
                    af[i], bfr[j], acc[i][j], 0, 0, 0);

        if (more) {
            __syncthreads();
#pragma unroll
            for (int q = 0; q < 4; ++q) {
                ushort4 w;
                w.x = csb[(int)va[q].x & 15];
                w.y = csb[(int)va[q].y & 15];
                w.z = csb[(int)va[q].z & 15];
                w.w = csb[(int)va[q].w & 15];
                *(ushort4*)&Ys[arow][acol + 4 * q] = w;
            }
#pragma unroll
            for (int k = 0; k < 16; ++k) Ps[bn][bkq + k] = f2bf(vb[k]);
            __syncthreads();
        }
    }

#pragma unroll
    for (int i = 0; i < 4; ++i)
#pragma unroll
        for (int j = 0; j < 4; ++j)
#pragma unroll
            for (int r = 0; r < 4; ++r) {
                const int row = wr + i * 16 + (lane >> 4) * 4 + r;
                const int col = wc + j * 16 + l15;
                Xhat[(size_t)(m0 + row) * TQ_D + n0 + col] = acc[i][j][r];
            }
}

// ---------------------------------------------------------------------------
extern "C" void kernel_launch(void* const* d_in, const int* in_sizes, int n_in,
                              void* d_out, int out_size, void* d_ws, size_t ws_size,
                              hipStream_t stream)
{
    const float* x    = (const float*)d_in[0];   // [N, 1024]
    const float* Pi   = (const float*)d_in[1];   // [1024, 1024]
    const float* cent = (const float*)d_in[2];   // [16]
    float* out = (float*)d_out;

    const int ND = in_sizes[0];      // N * 1024
    const int N  = ND / TQ_D;        // 4096

    float* xhat = out;               // output 0 (scratch: counter+list pre-K2)
    float* oidx = out + ND;          // output 1: indices as float

    unsigned* counter = (unsigned*)xhat;
    unsigned* list    = (unsigned*)xhat + 16;
    const unsigned cap = (unsigned)(ND - 16);

    hipMemsetAsync(counter, 0, 4, stream);   // zero suspect counter

    dim3 grid(TQ_D / 128, N / 128);  // (8, 32) = 256 blocks

    // Pass 1: 4-term MFMA rotate+quantize (8 waves/block) -> indices + suspects.
    tq_rq_mfma<<<grid, 512, 0, stream>>>(x, Pi, cent, oidx, counter, list, cap);

    // Pass 2: exact recompute of suspects (R9 realization), LDS-staged.
    tq_fixup_lds<<<1024, 256, 0, stream>>>(x, Pi, cent, oidx, counter, list, cap);

    // Pass 3: dequant + unrotate (MFMA) -> xhat (overwrites scratch).
    tq_dq_mfma<<<grid, 256, 0, stream>>>(oidx, Pi, cent, xhat);
}

// Round 24
// 123.886 us; speedup vs baseline: 1.9419x; 1.1598x over previous
//
#include <hip/hip_runtime.h>
#include <hip/hip_bf16.h>

#define TQ_D   1024
#define TQ_KC  16
#define MERGE_K 512          // OpenBLAS KC-panel boundary (proven R9)
#define TQ_TOL  1.0e-4f      // ~50 sigma of 4-term MFMA vs serial-f32 error
#define LCAP    1024         // per-block LDS suspect-list capacity

typedef __attribute__((ext_vector_type(8))) short bf16x8;
typedef __attribute__((ext_vector_type(4))) float f32x4;

__device__ __forceinline__ unsigned short f2bf(float f) {
    union { __hip_bfloat16 h; unsigned short s; } u;
    u.h = __float2bfloat16(f);
    return u.s;
}
__device__ __forceinline__ float bf2f(unsigned short s) {
    union { unsigned int u; float f; } v;
    v.u = (unsigned int)s << 16;
    return v.f;
}

// ---------------------------------------------------------------------------
// K1-MFMA (4-term, 8-wave, 128x64 tile): y = x @ Pi^T via bf16 hi/lo split
// with all four terms, f32 MFMA accum. 512 blocks (2/CU -> 16 waves/CU, 50%
// occupancy; R23's 128x128 grid was 1 block/CU = 25% cap). 8 waves in a 4x2
// grid of 32x32 wave-tiles (acc[2][2]). Literal f32 argmin; suspects
// (dist < TOL) aggregated per-block in LDS, one global atomicAdd per block.
// ---------------------------------------------------------------------------
__global__ __launch_bounds__(512)
void tq_rq_mfma(const float* __restrict__ X,
                const float* __restrict__ Pi,
                const float* __restrict__ Cent,
                float* __restrict__ OutIdx,
                unsigned* __restrict__ Counter,
                unsigned* __restrict__ List,
                unsigned cap)
{
    __shared__ unsigned short XhS[128][40];
    __shared__ unsigned short XlS[128][40];
    __shared__ unsigned short PhS[64][40];
    __shared__ unsigned short PlS[64][40];
    __shared__ unsigned lcount;
    __shared__ unsigned gbase;
    __shared__ unsigned llist[LCAP];

    const int tid  = threadIdx.x;
    const int lane = tid & 63;
    const int wv   = tid >> 6;          // 0..7
    const int m0 = blockIdx.y * 128;
    const int n0 = blockIdx.x * 64;
    const int wr = (wv >> 1) * 32;      // wave row origin (0/32/64/96)
    const int wc = (wv & 1) * 32;       // wave col origin (0/32)
    const int l15 = lane & 15;
    const int k8  = (lane >> 4) * 8;

    // staging: A = 128 rows x 32 k (8 floats/thread); B = 64 rows x 32 k (4)
    const int srow = tid >> 2;          // 0..127
    const int scol = (tid & 3) * 8;     // 0/8/16/24
    const int brow = tid >> 3;          // 0..63
    const int bcol = (tid & 7) * 4;     // 0..28

    const float* aP = X  + (size_t)(m0 + srow) * TQ_D + scol;
    const float* bP = Pi + (size_t)(n0 + brow) * TQ_D + bcol;

    if (tid == 0) lcount = 0;

    f32x4 acc[2][2];
#pragma unroll
    for (int i = 0; i < 2; ++i)
#pragma unroll
        for (int j = 0; j < 2; ++j)
#pragma unroll
            for (int r = 0; r < 4; ++r) acc[i][j][r] = 0.0f;

    float4 va[2], vb;
#pragma unroll
    for (int q = 0; q < 2; ++q) va[q] = *(const float4*)(aP + 4 * q);
    vb = *(const float4*)(bP);

#pragma unroll
    for (int q = 0; q < 2; ++q) {
        ushort4 ah, al;
        const float* fa = (const float*)&va[q];
        ah.x = f2bf(fa[0]); al.x = f2bf(fa[0] - bf2f(ah.x));
        ah.y = f2bf(fa[1]); al.y = f2bf(fa[1] - bf2f(ah.y));
        ah.z = f2bf(fa[2]); al.z = f2bf(fa[2] - bf2f(ah.z));
        ah.w = f2bf(fa[3]); al.w = f2bf(fa[3] - bf2f(ah.w));
        *(ushort4*)&XhS[srow][scol + 4 * q] = ah;
        *(ushort4*)&XlS[srow][scol + 4 * q] = al;
    }
    {
        ushort4 bh, bl;
        const float* fb = (const float*)&vb;
        bh.x = f2bf(fb[0]); bl.x = f2bf(fb[0] - bf2f(bh.x));
        bh.y = f2bf(fb[1]); bl.y = f2bf(fb[1] - bf2f(bh.y));
        bh.z = f2bf(fb[2]); bl.z = f2bf(fb[2] - bf2f(bh.z));
        bh.w = f2bf(fb[3]); bl.w = f2bf(fb[3] - bf2f(bh.w));
        *(ushort4*)&PhS[brow][bcol] = bh;
        *(ushort4*)&PlS[brow][bcol] = bl;
    }
    __syncthreads();   // also covers lcount init

    for (int kt = 0; kt < 32; ++kt) {
        const bool more = (kt + 1) < 32;
        if (more) {
            const float* ap = aP + (kt + 1) * 32;
            const float* bp = bP + (kt + 1) * 32;
#pragma unroll
            for (int q = 0; q < 2; ++q) va[q] = *(const float4*)(ap + 4 * q);
            vb = *(const float4*)(bp);
        }

        bf16x8 afh[2], afl[2], bfh[2], bfl[2];
#pragma unroll
        for (int i = 0; i < 2; ++i) {
            afh[i] = *(const bf16x8*)&XhS[wr + i * 16 + l15][k8];
            afl[i] = *(const bf16x8*)&XlS[wr + i * 16 + l15][k8];
        }
#pragma unroll
        for (int j = 0; j < 2; ++j) {
            bfh[j] = *(const bf16x8*)&PhS[wc + j * 16 + l15][k8];
            bfl[j] = *(const bf16x8*)&PlS[wc + j * 16 + l15][k8];
        }

#pragma unroll
        for (int i = 0; i < 2; ++i)
#pragma unroll
            for (int j = 0; j < 2; ++j) {
                acc[i][j] = __builtin_amdgcn_mfma_f32_16x16x32_bf16(
                    afh[i], bfh[j], acc[i][j], 0, 0, 0);
                acc[i][j] = __builtin_amdgcn_mfma_f32_16x16x32_bf16(
                    afl[i], bfh[j], acc[i][j], 0, 0, 0);
                acc[i][j] = __builtin_amdgcn_mfma_f32_16x16x32_bf16(
                    afh[i], bfl[j], acc[i][j], 0, 0, 0);
                acc[i][j] = __builtin_amdgcn_mfma_f32_16x16x32_bf16(
                    afl[i], bfl[j], acc[i][j], 0, 0, 0);
            }

        if (more) {
            __syncthreads();
#pragma unroll
            for (int q = 0; q < 2; ++q) {
                ushort4 ah, al;
                const float* fa = (const float*)&va[q];
                ah.x = f2bf(fa[0]); al.x = f2bf(fa[0] - bf2f(ah.x));
                ah.y = f2bf(fa[1]); al.y = f2bf(fa[1] - bf2f(ah.y));
                ah.z = f2bf(fa[2]); al.z = f2bf(fa[2] - bf2f(ah.z));
                ah.w = f2bf(fa[3]); al.w = f2bf(fa[3] - bf2f(ah.w));
                *(ushort4*)&XhS[srow][scol + 4 * q] = ah;
                *(ushort4*)&XlS[srow][scol + 4 * q] = al;
            }
            {
                ushort4 bh, bl;
                const float* fb = (const float*)&vb;
                bh.x = f2bf(fb[0]); bl.x = f2bf(fb[0] - bf2f(bh.x));
                bh.y = f2bf(fb[1]); bl.y = f2bf(fb[1] - bf2f(bh.y));
                bh.z = f2bf(fb[2]); bl.z = f2bf(fb[2] - bf2f(bh.z));
                bh.w = f2bf(fb[3]); bl.w = f2bf(fb[3] - bf2f(bh.w));
                *(ushort4*)&PhS[brow][bcol] = bh;
                *(ushort4*)&PlS[brow][bcol] = bl;
            }
            __syncthreads();
        }
    }

    float c[TQ_KC];
#pragma unroll
    for (int q = 0; q < TQ_KC; ++q) c[q] = Cent[q];

#pragma unroll
    for (int i = 0; i < 2; ++i)
#pragma unroll
        for (int j = 0; j < 2; ++j)
#pragma unroll
            for (int r = 0; r < 4; ++r) {
                const int row = m0 + wr + i * 16 + (lane >> 4) * 4 + r;
                const int col = n0 + wc + j * 16 + l15;
                const float y = acc[i][j][r];
                int best = 0;
                float bd = fabsf(y - c[0]);
#pragma unroll
                for (int q = 1; q < TQ_KC; ++q) {
                    const float d = fabsf(y - c[q]);
                    if (d < bd) { bd = d; best = q; }
                }
                float dist = 1e30f;
#pragma unroll
                for (int q = 0; q < TQ_KC - 1; ++q) {
                    const float mid = 0.5f * (c[q] + c[q + 1]);
                    dist = fminf(dist, fabsf(y - mid));
                }
                if (dist < TQ_TOL) {
                    const unsigned id = ((unsigned)row << 10) | (unsigned)col;
                    const unsigned ls = atomicAdd(&lcount, 1u);
                    if (ls < LCAP) {
                        llist[ls] = id;
                    } else {
                        const unsigned gs = atomicAdd(Counter, 1u);
                        if (gs < cap) List[gs] = id;
                    }
                }
                OutIdx[(size_t)row * TQ_D + col] = (float)best;
            }

    __syncthreads();
    if (tid == 0) {
        const unsigned cnt = min(lcount, (unsigned)LCAP);
        gbase = (cnt > 0) ? atomicAdd(Counter, cnt) : 0u;
    }
    __syncthreads();
    const unsigned cnt = min(lcount, (unsigned)LCAP);
    for (unsigned s = tid; s < cnt; s += 512) {
        const unsigned g = gbase + s;
        if (g < cap) List[g] = llist[s];
    }
}

// ---------------------------------------------------------------------------
// Fixup (LDS-staged, proven R21-R23): 8 suspects/block; cooperative 64KB row
// staging; two independent 512-wide serial panel chains per suspect (exact
// R9 realization), merge a1+a2, literal argmin.
// ---------------------------------------------------------------------------
__global__ __launch_bounds__(256)
void tq_fixup_lds(const float* __restrict__ X,
                  const float* __restrict__ Pi,
                  const float* __restrict__ Cent,
                  float* __restrict__ OutIdx,
                  const unsigned* __restrict__ Counter,
                  const unsigned* __restrict__ List,
                  unsigned cap)
{
    __shared__ float Rows[8][2][1024];   // [suspect][0=X,1=Pi][k]
    __shared__ float part[8][2];
    __shared__ unsigned ids[8];

    const int tid = threadIdx.x;
    const unsigned count = min(*Counter, cap);

    for (unsigned base = blockIdx.x * 8; base < count; base += gridDim.x * 8) {
        const unsigned nsus = min(8u, count - base);

        if (tid < 8) ids[tid] = (tid < nsus) ? List[base + tid] : 0u;
        __syncthreads();

#pragma unroll
        for (int q = 0; q < 16; ++q) {
            const int lin = q * 256 + tid;
            const int sus = lin >> 9;            // 512 float4 per suspect
            const int rowsel = (lin >> 8) & 1;   // 0 = X row, 1 = Pi row
            const int f4 = lin & 255;
            if ((unsigned)sus < nsus) {
                const unsigned id = ids[sus];
                const int m = id >> 10;
                const int n = id & (TQ_D - 1);
                const float* src = rowsel ? (Pi + (size_t)n * TQ_D)
                                          : (X + (size_t)m * TQ_D);
                *(float4*)&Rows[sus][rowsel][f4 * 4] =
                    *(const float4*)(src + f4 * 4);
            }
        }
        __syncthreads();

        if (tid < 16 && (unsigned)(tid >> 1) < nsus) {
            const int sus = tid >> 1;
            const int p = tid & 1;
            const int kb = p * MERGE_K;
            float a = 0.0f;
            for (int k = 0; k < MERGE_K; k += 4) {
                const float4 xa = *(const float4*)&Rows[sus][0][kb + k];
                const float4 pa = *(const float4*)&Rows[sus][1][kb + k];
                a = fmaf(xa.x, pa.x, a);
                a = fmaf(xa.y, pa.y, a);
                a = fmaf(xa.z, pa.z, a);
                a = fmaf(xa.w, pa.w, a);
            }
            part[sus][p] = a;
        }
        __syncthreads();

        if (tid < (int)nsus) {
            const float y = part[tid][0] + part[tid][1];   // exact R9 merge
            float c[TQ_KC];
#pragma unroll
            for (int q = 0; q < TQ_KC; ++q) c[q] = Cent[q];
            int best = 0;
            float bd = fabsf(y - c[0]);
#pragma unroll
            for (int q = 1; q < TQ_KC; ++q) {
                const float d = fabsf(y - c[q]);
                if (d < bd) { bd = d; best = q; }
            }
            const unsigned id = ids[tid];
            OutIdx[(size_t)(id >> 10) * TQ_D + (id & (TQ_D - 1))] = (float)best;
        }
        __syncthreads();
    }
}

// ---------------------------------------------------------------------------
// Kernel 2 (MFMA, proven R15): x_hat = dequant(idx) @ Pi, bf16 MFMA f32-acc.
// ---------------------------------------------------------------------------
__global__ __launch_bounds__(256)
void tq_dq_mfma(const float* __restrict__ IdxF,
                const float* __restrict__ Pi,
                const float* __restrict__ Cent,
                float* __restrict__ Xhat)
{
    __shared__ unsigned short Ys[128][40];
    __shared__ unsigned short Ps[128][40];
    __shared__ unsigned short csb[TQ_KC];

    const int tid  = threadIdx.x;
    const int lane = tid & 63;
    const int wv   = tid >> 6;
    const int m0 = blockIdx.y * 128;
    const int n0 = blockIdx.x * 128;
    const int wr = (wv >> 1) * 64;
    const int wc = (wv & 1) * 64;
    const int l15 = lane & 15;
    const int k8  = (lane >> 4) * 8;

    const int arow = tid >> 1;
    const int acol = (tid & 1) * 16;
    const int bn   = tid & 127;
    const int bkq  = (tid >> 7) * 16;

    const float* aP = IdxF + (size_t)(m0 + arow) * TQ_D + acol;
    const float* bP = Pi + (size_t)bkq * TQ_D + n0 + bn;

    if (tid < TQ_KC) csb[tid] = f2bf(Cent[tid]);

    f32x4 acc[4][4];
#pragma unroll
    for (int i = 0; i < 4; ++i)
#pragma unroll
        for (int j = 0; j < 4; ++j)
#pragma unroll
            for (int r = 0; r < 4; ++r) acc[i][j][r] = 0.0f;

    float4 va[4];
    float  vb[16];
#pragma unroll
    for (int q = 0; q < 4; ++q) va[q] = *(const float4*)(aP + 4 * q);
#pragma unroll
    for (int k = 0; k < 16; ++k) vb[k] = bP[(size_t)k * TQ_D];

    __syncthreads();   // csb ready

#pragma unroll
    for (int q = 0; q < 4; ++q) {
        ushort4 w;
        w.x = csb[(int)va[q].x & 15];
        w.y = csb[(int)va[q].y & 15];
        w.z = csb[(int)va[q].z & 15];
        w.w = csb[(int)va[q].w & 15];
        *(ushort4*)&Ys[arow][acol + 4 * q] = w;
    }
#pragma unroll
    for (int k = 0; k < 16; ++k) Ps[bn][bkq + k] = f2bf(vb[k]);
    __syncthreads();

    for (int kt = 0; kt < 32; ++kt) {
        const bool more = (kt + 1) < 32;
        if (more) {
            const float* ap = aP + (kt + 1) * 32;
            const float* bp = bP + (size_t)(kt + 1) * 32 * TQ_D;
#pragma unroll
            for (int q = 0; q < 4; ++q) va[q] = *(const float4*)(ap + 4 * q);
#pragma unroll
            for (int k = 0; k < 16; ++k) vb[k] = bp[(size_t)k * TQ_D];
        }

        bf16x8 af[4], bfr[4];
#pragma unroll
        for (int i = 0; i < 4; ++i)
            af[i] = *(const bf16x8*)&Ys[wr + i * 16 + l15][k8];
#pragma unroll
        for (int j = 0; j < 4; ++j)
            bfr[j] = *(const bf16x8*)&Ps[wc + j * 16 + l15][k8];

#pragma unroll
        for (int i = 0; i < 4; ++i)
#pragma unroll
            for (int j = 0; j < 4; ++j)
                acc[i][j] = __builtin_amdgcn_mfma_f32_16x16x32_bf16(
                    af[i], bfr[j], acc[i][j], 0, 0, 0);

        if (more) {
            __syncthreads();
#pragma unroll
            for (int q = 0; q < 4; ++q) {
                ushort4 w;
                w.x = csb[(int)va[q].x & 15];
                w.y = csb[(int)va[q].y & 15];
                w.z = csb[(int)va[q].z & 15];
                w.w = csb[(int)va[q].w & 15];
                *(ushort4*)&Ys[arow][acol + 4 * q] = w;
            }
#pragma unroll
            for (int k = 0; k < 16; ++k) Ps[bn][bkq + k] = f2bf(vb[k]);
            __syncthreads();
        }
    }

#pragma unroll
    for (int i = 0; i < 4; ++i)
#pragma unroll
        for (int j = 0; j < 4; ++j)
#pragma unroll
            for (int r = 0; r < 4; ++r) {
                const int row = wr + i * 16 + (lane >> 4) * 4 + r;
                const int col = wc + j * 16 + l15;
                Xhat[(size_t)(m0 + row) * TQ_D + n0 + col] = acc[i][j][r];
            }
}

// ---------------------------------------------------------------------------
extern "C" void kernel_launch(void* const* d_in, const int* in_sizes, int n_in,
                              void* d_out, int out_size, void* d_ws, size_t ws_size,
                              hipStream_t stream)
{
    const float* x    = (const float*)d_in[0];   // [N, 1024]
    const float* Pi   = (const float*)d_in[1];   // [1024, 1024]
    const float* cent = (const float*)d_in[2];   // [16]
    float* out = (float*)d_out;

    const int ND = in_sizes[0];      // N * 1024
    const int N  = ND / TQ_D;        // 4096

    float* xhat = out;               // output 0 (scratch: counter+list pre-K2)
    float* oidx = out + ND;          // output 1: indices as float

    unsigned* counter = (unsigned*)xhat;
    unsigned* list    = (unsigned*)xhat + 16;
    const unsigned cap = (unsigned)(ND - 16);

    hipMemsetAsync(counter, 0, 4, stream);   // zero suspect counter

    // Pass 1: 4-term MFMA rotate+quantize (128x64 tile, 512 blocks, 8 waves).
    dim3 grid1(TQ_D / 64, N / 128);  // (16, 32) = 512 blocks
    tq_rq_mfma<<<grid1, 512, 0, stream>>>(x, Pi, cent, oidx, counter, list, cap);

    // Pass 2: exact recompute of suspects (R9 realization), LDS-staged.
    tq_fixup_lds<<<1024, 256, 0, stream>>>(x, Pi, cent, oidx, counter, list, cap);

    // Pass 3: dequant + unrotate (MFMA) -> xhat (overwrites scratch).
    dim3 grid3(TQ_D / 128, N / 128); // (8, 32) = 256 blocks
    tq_dq_mfma<<<grid3, 256, 0, stream>>>(oidx, Pi, cent, xhat);
}

// Round 25
// 107.442 us; speedup vs baseline: 2.2391x; 1.1530x over previous
//
#include <hip/hip_runtime.h>
#include <hip/hip_bf16.h>

#define TQ_D   1024
#define TQ_KC  16
#define MERGE_K 512          // OpenBLAS KC-panel boundary (proven R9)
#define TQ_TOL  1.0e-4f      // ~50 sigma of 4-term MFMA vs serial-f32 error
#define LCAP    1024         // per-block LDS suspect-list capacity

typedef __attribute__((ext_vector_type(8))) short bf16x8;
typedef __attribute__((ext_vector_type(4))) float f32x4;

__device__ __forceinline__ unsigned short f2bf(float f) {
    union { __hip_bfloat16 h; unsigned short s; } u;
    u.h = __float2bfloat16(f);
    return u.s;
}
__device__ __forceinline__ float bf2f(unsigned short s) {
    union { unsigned int u; float f; } v;
    v.u = (unsigned int)s << 16;
    return v.f;
}

// ---------------------------------------------------------------------------
// K1-MFMA (4-term, 8-wave, 128x64 tile — proven R24, 59us): y = x @ Pi^T via
// bf16 hi/lo split, f32 MFMA accum, literal f32 argmin; suspects (dist < TOL)
// aggregated per-block in LDS, one global atomicAdd per block.
// ---------------------------------------------------------------------------
__global__ __launch_bounds__(512)
void tq_rq_mfma(const float* __restrict__ X,
                const float* __restrict__ Pi,
                const float* __restrict__ Cent,
                float* __restrict__ OutIdx,
                unsigned* __restrict__ Counter,
                unsigned* __restrict__ List,
                unsigned cap)
{
    __shared__ unsigned short XhS[128][40];
    __shared__ unsigned short XlS[128][40];
    __shared__ unsigned short PhS[64][40];
    __shared__ unsigned short PlS[64][40];
    __shared__ unsigned lcount;
    __shared__ unsigned gbase;
    __shared__ unsigned llist[LCAP];

    const int tid  = threadIdx.x;
    const int lane = tid & 63;
    const int wv   = tid >> 6;          // 0..7
    const int m0 = blockIdx.y * 128;
    const int n0 = blockIdx.x * 64;
    const int wr = (wv >> 1) * 32;      // wave row origin (0/32/64/96)
    const int wc = (wv & 1) * 32;       // wave col origin (0/32)
    const int l15 = lane & 15;
    const int k8  = (lane >> 4) * 8;

    const int srow = tid >> 2;          // 0..127
    const int scol = (tid & 3) * 8;     // 0/8/16/24
    const int brow = tid >> 3;          // 0..63
    const int bcol = (tid & 7) * 4;     // 0..28

    const float* aP = X  + (size_t)(m0 + srow) * TQ_D + scol;
    const float* bP = Pi + (size_t)(n0 + brow) * TQ_D + bcol;

    if (tid == 0) lcount = 0;

    f32x4 acc[2][2];
#pragma unroll
    for (int i = 0; i < 2; ++i)
#pragma unroll
        for (int j = 0; j < 2; ++j)
#pragma unroll
            for (int r = 0; r < 4; ++r) acc[i][j][r] = 0.0f;

    float4 va[2], vb;
#pragma unroll
    for (int q = 0; q < 2; ++q) va[q] = *(const float4*)(aP + 4 * q);
    vb = *(const float4*)(bP);

#pragma unroll
    for (int q = 0; q < 2; ++q) {
        ushort4 ah, al;
        const float* fa = (const float*)&va[q];
        ah.x = f2bf(fa[0]); al.x = f2bf(fa[0] - bf2f(ah.x));
        ah.y = f2bf(fa[1]); al.y = f2bf(fa[1] - bf2f(ah.y));
        ah.z = f2bf(fa[2]); al.z = f2bf(fa[2] - bf2f(ah.z));
        ah.w = f2bf(fa[3]); al.w = f2bf(fa[3] - bf2f(ah.w));
        *(ushort4*)&XhS[srow][scol + 4 * q] = ah;
        *(ushort4*)&XlS[srow][scol + 4 * q] = al;
    }
    {
        ushort4 bh, bl;
        const float* fb = (const float*)&vb;
        bh.x = f2bf(fb[0]); bl.x = f2bf(fb[0] - bf2f(bh.x));
        bh.y = f2bf(fb[1]); bl.y = f2bf(fb[1] - bf2f(bh.y));
        bh.z = f2bf(fb[2]); bl.z = f2bf(fb[2] - bf2f(bh.z));
        bh.w = f2bf(fb[3]); bl.w = f2bf(fb[3] - bf2f(bh.w));
        *(ushort4*)&PhS[brow][bcol] = bh;
        *(ushort4*)&PlS[brow][bcol] = bl;
    }
    __syncthreads();   // also covers lcount init

    for (int kt = 0; kt < 32; ++kt) {
        const bool more = (kt + 1) < 32;
        if (more) {
            const float* ap = aP + (kt + 1) * 32;
            const float* bp = bP + (kt + 1) * 32;
#pragma unroll
            for (int q = 0; q < 2; ++q) va[q] = *(const float4*)(ap + 4 * q);
            vb = *(const float4*)(bp);
        }

        bf16x8 afh[2], afl[2], bfh[2], bfl[2];
#pragma unroll
        for (int i = 0; i < 2; ++i) {
            afh[i] = *(const bf16x8*)&XhS[wr + i * 16 + l15][k8];
            afl[i] = *(const bf16x8*)&XlS[wr + i * 16 + l15][k8];
        }
#pragma unroll
        for (int j = 0; j < 2; ++j) {
            bfh[j] = *(const bf16x8*)&PhS[wc + j * 16 + l15][k8];
            bfl[j] = *(const bf16x8*)&PlS[wc + j * 16 + l15][k8];
        }

#pragma unroll
        for (int i = 0; i < 2; ++i)
#pragma unroll
            for (int j = 0; j < 2; ++j) {
                acc[i][j] = __builtin_amdgcn_mfma_f32_16x16x32_bf16(
                    afh[i], bfh[j], acc[i][j], 0, 0, 0);
                acc[i][j] = __builtin_amdgcn_mfma_f32_16x16x32_bf16(
                    afl[i], bfh[j], acc[i][j], 0, 0, 0);
                acc[i][j] = __builtin_amdgcn_mfma_f32_16x16x32_bf16(
                    afh[i], bfl[j], acc[i][j], 0, 0, 0);
                acc[i][j] = __builtin_amdgcn_mfma_f32_16x16x32_bf16(
                    afl[i], bfl[j], acc[i][j], 0, 0, 0);
            }

        if (more) {
            __syncthreads();
#pragma unroll
            for (int q = 0; q < 2; ++q) {
                ushort4 ah, al;
                const float* fa = (const float*)&va[q];
                ah.x = f2bf(fa[0]); al.x = f2bf(fa[0] - bf2f(ah.x));
                ah.y = f2bf(fa[1]); al.y = f2bf(fa[1] - bf2f(ah.y));
                ah.z = f2bf(fa[2]); al.z = f2bf(fa[2] - bf2f(ah.z));
                ah.w = f2bf(fa[3]); al.w = f2bf(fa[3] - bf2f(ah.w));
                *(ushort4*)&XhS[srow][scol + 4 * q] = ah;
                *(ushort4*)&XlS[srow][scol + 4 * q] = al;
            }
            {
                ushort4 bh, bl;
                const float* fb = (const float*)&vb;
                bh.x = f2bf(fb[0]); bl.x = f2bf(fb[0] - bf2f(bh.x));
                bh.y = f2bf(fb[1]); bl.y = f2bf(fb[1] - bf2f(bh.y));
                bh.z = f2bf(fb[2]); bl.z = f2bf(fb[2] - bf2f(bh.z));
                bh.w = f2bf(fb[3]); bl.w = f2bf(fb[3] - bf2f(bh.w));
                *(ushort4*)&PhS[brow][bcol] = bh;
                *(ushort4*)&PlS[brow][bcol] = bl;
            }
            __syncthreads();
        }
    }

    float c[TQ_KC];
#pragma unroll
    for (int q = 0; q < TQ_KC; ++q) c[q] = Cent[q];

#pragma unroll
    for (int i = 0; i < 2; ++i)
#pragma unroll
        for (int j = 0; j < 2; ++j)
#pragma unroll
            for (int r = 0; r < 4; ++r) {
                const int row = m0 + wr + i * 16 + (lane >> 4) * 4 + r;
                const int col = n0 + wc + j * 16 + l15;
                const float y = acc[i][j][r];
                int best = 0;
                float bd = fabsf(y - c[0]);
#pragma unroll
                for (int q = 1; q < TQ_KC; ++q) {
                    const float d = fabsf(y - c[q]);
                    if (d < bd) { bd = d; best = q; }
                }
                float dist = 1e30f;
#pragma unroll
                for (int q = 0; q < TQ_KC - 1; ++q) {
                    const float mid = 0.5f * (c[q] + c[q + 1]);
                    dist = fminf(dist, fabsf(y - mid));
                }
                if (dist < TQ_TOL) {
                    const unsigned id = ((unsigned)row << 10) | (unsigned)col;
                    const unsigned ls = atomicAdd(&lcount, 1u);
                    if (ls < LCAP) {
                        llist[ls] = id;
                    } else {
                        const unsigned gs = atomicAdd(Counter, 1u);
                        if (gs < cap) List[gs] = id;
                    }
                }
                OutIdx[(size_t)row * TQ_D + col] = (float)best;
            }

    __syncthreads();
    if (tid == 0) {
        const unsigned cnt = min(lcount, (unsigned)LCAP);
        gbase = (cnt > 0) ? atomicAdd(Counter, cnt) : 0u;
    }
    __syncthreads();
    const unsigned cnt = min(lcount, (unsigned)LCAP);
    for (unsigned s = tid; s < cnt; s += 512) {
        const unsigned g = gbase + s;
        if (g < cap) List[g] = llist[s];
    }
}

// ---------------------------------------------------------------------------
// Fixup (LDS-staged, proven R21-R24): 8 suspects/block; cooperative 64KB row
// staging; two independent 512-wide serial panel chains per suspect (exact
// R9 realization), merge a1+a2, literal argmin.
// ---------------------------------------------------------------------------
__global__ __launch_bounds__(256)
void tq_fixup_lds(const float* __restrict__ X,
                  const float* __restrict__ Pi,
                  const float* __restrict__ Cent,
                  float* __restrict__ OutIdx,
                  const unsigned* __restrict__ Counter,
                  const unsigned* __restrict__ List,
                  unsigned cap)
{
    __shared__ float Rows[8][2][1024];   // [suspect][0=X,1=Pi][k]
    __shared__ float part[8][2];
    __shared__ unsigned ids[8];

    const int tid = threadIdx.x;
    const unsigned count = min(*Counter, cap);

    for (unsigned base = blockIdx.x * 8; base < count; base += gridDim.x * 8) {
        const unsigned nsus = min(8u, count - base);

        if (tid < 8) ids[tid] = (tid < nsus) ? List[base + tid] : 0u;
        __syncthreads();

#pragma unroll
        for (int q = 0; q < 16; ++q) {
            const int lin = q * 256 + tid;
            const int sus = lin >> 9;            // 512 float4 per suspect
            const int rowsel = (lin >> 8) & 1;   // 0 = X row, 1 = Pi row
            const int f4 = lin & 255;
            if ((unsigned)sus < nsus) {
                const unsigned id = ids[sus];
                const int m = id >> 10;
                const int n = id & (TQ_D - 1);
                const float* src = rowsel ? (Pi + (size_t)n * TQ_D)
                                          : (X + (size_t)m * TQ_D);
                *(float4*)&Rows[sus][rowsel][f4 * 4] =
                    *(const float4*)(src + f4 * 4);
            }
        }
        __syncthreads();

        if (tid < 16 && (unsigned)(tid >> 1) < nsus) {
            const int sus = tid >> 1;
            const int p = tid & 1;
            const int kb = p * MERGE_K;
            float a = 0.0f;
            for (int k = 0; k < MERGE_K; k += 4) {
                const float4 xa = *(const float4*)&Rows[sus][0][kb + k];
                const float4 pa = *(const float4*)&Rows[sus][1][kb + k];
                a = fmaf(xa.x, pa.x, a);
                a = fmaf(xa.y, pa.y, a);
                a = fmaf(xa.z, pa.z, a);
                a = fmaf(xa.w, pa.w, a);
            }
            part[sus][p] = a;
        }
        __syncthreads();

        if (tid < (int)nsus) {
            const float y = part[tid][0] + part[tid][1];   // exact R9 merge
            float c[TQ_KC];
#pragma unroll
            for (int q = 0; q < TQ_KC; ++q) c[q] = Cent[q];
            int best = 0;
            float bd = fabsf(y - c[0]);
#pragma unroll
            for (int q = 1; q < TQ_KC; ++q) {
                const float d = fabsf(y - c[q]);
                if (d < bd) { bd = d; best = q; }
            }
            const unsigned id = ids[tid];
            OutIdx[(size_t)(id >> 10) * TQ_D + (id & (TQ_D - 1))] = (float)best;
        }
        __syncthreads();
    }
}

// ---------------------------------------------------------------------------
// Kernel 2 (MFMA, NEW 8-wave 128x64): x_hat = dequant(idx) @ Pi, bf16 MFMA
// f32-acc. 512 blocks (2/CU -> 16 waves/CU; old 4-wave/256-block version was
// 58us at 1 block/CU). A staged via LDS centroid LUT; B = Pi rows transposed
// into Ps[n][k] (coalesced float4 reads, scalar bf16 writes).
// ---------------------------------------------------------------------------
__global__ __launch_bounds__(512)
void tq_dq_mfma(const float* __restrict__ IdxF,
                const float* __restrict__ Pi,
                const float* __restrict__ Cent,
                float* __restrict__ Xhat)
{
    __shared__ unsigned short Ys[128][40];   // y_hat bf16 [row][k]
    __shared__ unsigned short Ps[64][40];    // Pi^T bf16 [n][k]
    __shared__ unsigned short csb[TQ_KC];

    const int tid  = threadIdx.x;
    const int lane = tid & 63;
    const int wv   = tid >> 6;          // 0..7
    const int m0 = blockIdx.y * 128;
    const int n0 = blockIdx.x * 64;
    const int wr = (wv >> 1) * 32;      // wave row origin (0/32/64/96)
    const int wc = (wv & 1) * 32;       // wave col origin (0/32)
    const int l15 = lane & 15;
    const int k8  = (lane >> 4) * 8;

    // A staging: 128 rows x 32 k, 8 elements/thread
    const int srow = tid >> 2;          // 0..127
    const int scol = (tid & 3) * 8;     // 0/8/16/24
    // B staging: 32 k-rows x 64 n, 4 elements/thread (coalesced on n)
    const int bk = tid >> 4;            // 0..31
    const int bnq = (tid & 15) * 4;     // 0..60

    const float* aP = IdxF + (size_t)(m0 + srow) * TQ_D + scol;
    const float* bP = Pi + (size_t)bk * TQ_D + n0 + bnq;

    if (tid < TQ_KC) csb[tid] = f2bf(Cent[tid]);

    f32x4 acc[2][2];
#pragma unroll
    for (int i = 0; i < 2; ++i)
#pragma unroll
        for (int j = 0; j < 2; ++j)
#pragma unroll
            for (int r = 0; r < 4; ++r) acc[i][j][r] = 0.0f;

    float4 va[2], vb;
#pragma unroll
    for (int q = 0; q < 2; ++q) va[q] = *(const float4*)(aP + 4 * q);
    vb = *(const float4*)(bP);

    __syncthreads();   // csb ready

#pragma unroll
    for (int q = 0; q < 2; ++q) {
        ushort4 w;
        const float* fa = (const float*)&va[q];
        w.x = csb[(int)fa[0] & 15];
        w.y = csb[(int)fa[1] & 15];
        w.z = csb[(int)fa[2] & 15];
        w.w = csb[(int)fa[3] & 15];
        *(ushort4*)&Ys[srow][scol + 4 * q] = w;
    }
    {
        const float* fb = (const float*)&vb;
        Ps[bnq + 0][bk] = f2bf(fb[0]);
        Ps[bnq + 1][bk] = f2bf(fb[1]);
        Ps[bnq + 2][bk] = f2bf(fb[2]);
        Ps[bnq + 3][bk] = f2bf(fb[3]);
    }
    __syncthreads();

    for (int kt = 0; kt < 32; ++kt) {
        const bool more = (kt + 1) < 32;
        if (more) {
            const float* ap = aP + (kt + 1) * 32;
            const float* bp = bP + (size_t)(kt + 1) * 32 * TQ_D;
#pragma unroll
            for (int q = 0; q < 2; ++q) va[q] = *(const float4*)(ap + 4 * q);
            vb = *(const float4*)(bp);
        }

        bf16x8 af[2], bfr[2];
#pragma unroll
        for (int i = 0; i < 2; ++i)
            af[i] = *(const bf16x8*)&Ys[wr + i * 16 + l15][k8];
#pragma unroll
        for (int j = 0; j < 2; ++j)
            bfr[j] = *(const bf16x8*)&Ps[wc + j * 16 + l15][k8];

#pragma unroll
        for (int i = 0; i < 2; ++i)
#pragma unroll
            for (int j = 0; j < 2; ++j)
                acc[i][j] = __builtin_amdgcn_mfma_f32_16x16x32_bf16(
                    af[i], bfr[j], acc[i][j], 0, 0, 0);

        if (more) {
            __syncthreads();
#pragma unroll
            for (int q = 0; q < 2; ++q) {
                ushort4 w;
                const float* fa = (const float*)&va[q];
                w.x = csb[(int)fa[0] & 15];
                w.y = csb[(int)fa[1] & 15];
                w.z = csb[(int)fa[2] & 15];
                w.w = csb[(int)fa[3] & 15];
                *(ushort4*)&Ys[srow][scol + 4 * q] = w;
            }
            {
                const float* fb = (const float*)&vb;
                Ps[bnq + 0][bk] = f2bf(fb[0]);
                Ps[bnq + 1][bk] = f2bf(fb[1]);
                Ps[bnq + 2][bk] = f2bf(fb[2]);
                Ps[bnq + 3][bk] = f2bf(fb[3]);
            }
            __syncthreads();
        }
    }

#pragma unroll
    for (int i = 0; i < 2; ++i)
#pragma unroll
        for (int j = 0; j < 2; ++j)
#pragma unroll
            for (int r = 0; r < 4; ++r) {
                const int row = wr + i * 16 + (lane >> 4) * 4 + r;
                const int col = wc + j * 16 + l15;
                Xhat[(size_t)(m0 + row) * TQ_D + n0 + col] = acc[i][j][r];
            }
}

// ---------------------------------------------------------------------------
extern "C" void kernel_launch(void* const* d_in, const int* in_sizes, int n_in,
                              void* d_out, int out_size, void* d_ws, size_t ws_size,
                              hipStream_t stream)
{
    const float* x    = (const float*)d_in[0];   // [N, 1024]
    const float* Pi   = (const float*)d_in[1];   // [1024, 1024]
    const float* cent = (const float*)d_in[2];   // [16]
    float* out = (float*)d_out;

    const int ND = in_sizes[0];      // N * 1024
    const int N  = ND / TQ_D;        // 4096

    float* xhat = out;               // output 0 (scratch: counter+list pre-K2)
    float* oidx = out + ND;          // output 1: indices as float

    unsigned* counter = (unsigned*)xhat;
    unsigned* list    = (unsigned*)xhat + 16;
    const unsigned cap = (unsigned)(ND - 16);

    hipMemsetAsync(counter, 0, 4, stream);   // zero suspect counter

    // Pass 1: 4-term MFMA rotate+quantize (128x64 tile, 512 blocks, 8 waves).
    dim3 grid1(TQ_D / 64, N / 128);  // (16, 32) = 512 blocks
    tq_rq_mfma<<<grid1, 512, 0, stream>>>(x, Pi, cent, oidx, counter, list, cap);

    // Pass 2: exact recompute of suspects (R9 realization), LDS-staged.
    tq_fixup_lds<<<1024, 256, 0, stream>>>(x, Pi, cent, oidx, counter, list, cap);

    // Pass 3: dequant + unrotate (MFMA, 8-wave 128x64) -> xhat.
    tq_dq_mfma<<<grid1, 512, 0, stream>>>(oidx, Pi, cent, xhat);
}